// Round 9
// baseline (240.743 us; speedup 1.0000x reference)
//
#include <hip/hip_runtime.h>
#include <math.h>

#define B_ 4
#define S_ 2048
#define E_ 1024
#define H_ 16
#define D_ 64
#define M_ (B_*S_)
// 1/sqrt(2048) * log2(e): scale folded into Wq/bq so softmax uses exp2 directly
#define QSCALE (0.022097086912079608f * 1.4426950408889634f)

typedef __bf16 bf16_t;
typedef __bf16 bf16x8 __attribute__((ext_vector_type(8)));
typedef float  f32x4  __attribute__((ext_vector_type(4)));

// async global->LDS, 16B per lane. LDS dest must be linear (base + lane*16).
__device__ __forceinline__ void gload_lds16(const void* g, void* l) {
    __builtin_amdgcn_global_load_lds(
        (const __attribute__((address_space(1))) void*)g,
        (__attribute__((address_space(3))) void*)l, 16, 0, 0);
}
__device__ __forceinline__ bf16x8 ldsx8(const void* p) {
    return __builtin_bit_cast(bf16x8, *(const uint4*)p);
}
__device__ __forceinline__ unsigned short bf16bits(float x) {
    return __builtin_bit_cast(unsigned short, (bf16_t)x);
}
// swizzle for K-tile QK^T A-frag read rows {32c + 8a + 4kf + b}: f = (b + 2a) & 7
__device__ __forceinline__ int fk(int row) { return ((row & 3) + 2 * ((row >> 3) & 3)) & 7; }

// ---------------------------------------------------------------------------
// bf16 MFMA GEMM, C = A[M,K] x Bt[N,K]^T. BK=64, 4 waves, wave tile (BM/2)x(BN/2).
// Grid flattened + bijective XCD swizzle (requires nwg % 8 == 0).
// MODE 0: bf16 out + bias. MODE 2: QKV scatter; Q bias scaled by QSCALE;
// V written transposed as vt[bh][d][s].
// ---------------------------------------------------------------------------
template<int BM, int BN, int MODE>
__global__ __launch_bounds__(256) void gemm_bf16(
    const bf16_t* __restrict__ A, const bf16_t* __restrict__ Bt,
    bf16_t* __restrict__ ob0, bf16_t* __restrict__ ob1, bf16_t* __restrict__ ob2,
    const float* __restrict__ bias0, const float* __restrict__ bias1,
    const float* __restrict__ bias2,
    int M, int N, int K)
{
    constexpr int FM = BM / 32, FN = BN / 32;
    __shared__ bf16_t As[BM * 64];
    __shared__ bf16_t Bs[BN * 64];

    const int tid = threadIdx.x;
    const int w   = tid >> 6;
    const int wr  = w >> 1, wc = w & 1;
    const int lr  = tid & 15;
    const int lg  = (tid >> 4) & 3;

    // XCD-bijective block swizzle: 8 contiguous chunks, one per XCD
    const int nwg  = gridDim.x * gridDim.y;
    int bidf = blockIdx.y * gridDim.x + blockIdx.x;
    bidf = (bidf & 7) * (nwg >> 3) + (bidf >> 3);
    const int bm = (bidf / gridDim.x) * BM;
    const int bn = (bidf % gridDim.x) * BN;

    f32x4 acc[FM][FN] = {};

    for (int kk = 0; kk < K; kk += 64) {
        __syncthreads();
        #pragma unroll
        for (int i = 0; i < BM / 32; ++i) {
            int idx = i * 256 + tid;
            int row = idx >> 3, slot = idx & 7;
            gload_lds16(A + (size_t)(bm + row) * K + kk + (slot ^ (row & 7)) * 8,
                        (char*)As + idx * 16);
        }
        #pragma unroll
        for (int i = 0; i < BN / 32; ++i) {
            int idx = i * 256 + tid;
            int row = idx >> 3, slot = idx & 7;
            gload_lds16(Bt + (size_t)(bn + row) * K + kk + (slot ^ (row & 7)) * 8,
                        (char*)Bs + idx * 16);
        }
        __syncthreads();

        #pragma unroll
        for (int h = 0; h < 2; ++h) {
            bf16x8 af[FM], bfr[FN];
            #pragma unroll
            for (int m = 0; m < FM; ++m) {
                int row = wr * (BM / 2) + m * 16 + lr;
                af[m] = ldsx8((char*)As + row * 128 + (((4 * h + lg) ^ (row & 7)) << 4));
            }
            #pragma unroll
            for (int n = 0; n < FN; ++n) {
                int col = wc * (BN / 2) + n * 16 + lr;
                bfr[n] = ldsx8((char*)Bs + col * 128 + (((4 * h + lg) ^ (col & 7)) << 4));
            }
            #pragma unroll
            for (int m = 0; m < FM; ++m)
                #pragma unroll
                for (int n = 0; n < FN; ++n)
                    acc[m][n] = __builtin_amdgcn_mfma_f32_16x16x32_bf16(
                        af[m], bfr[n], acc[m][n], 0, 0, 0);
        }
    }

    #pragma unroll
    for (int n = 0; n < FN; ++n) {
        const int gcol = bn + wc * (BN / 2) + n * 16 + lr;
        if constexpr (MODE == 2) {
            const int p = gcol >> 10, nn = gcol & 1023;
            const float bv = (p == 0) ? bias0[nn] * QSCALE
                           : (p == 1) ? bias1[nn] : bias2[nn];
            #pragma unroll
            for (int m = 0; m < FM; ++m) {
                const int grow0 = bm + wr * (BM / 2) + m * 16 + lg * 4;
                if (p == 2) {   // V: write transposed [bh][d][s], 4 s contiguous
                    ushort4 o;
                    o.x = bf16bits(acc[m][n][0] + bv);
                    o.y = bf16bits(acc[m][n][1] + bv);
                    o.z = bf16bits(acc[m][n][2] + bv);
                    o.w = bf16bits(acc[m][n][3] + bv);
                    const int bb = grow0 >> 11, s = grow0 & 2047;
                    *(ushort4*)(ob2 + (((size_t)(bb << 10) + nn) << 11) + s) = o;
                } else {
                    bf16_t* o = (p == 0) ? ob0 : ob1;
                    #pragma unroll
                    for (int r = 0; r < 4; ++r)
                        o[((size_t)(grow0 + r) << 10) + nn] = (bf16_t)(acc[m][n][r] + bv);
                }
            }
        } else {
            const float bv = bias0[gcol];
            #pragma unroll
            for (int m = 0; m < FM; ++m)
                #pragma unroll
                for (int r = 0; r < 4; ++r) {
                    const int grow = bm + wr * (BM / 2) + m * 16 + lg * 4 + r;
                    ob0[(size_t)grow * N + gcol] = (bf16_t)(acc[m][n][r] + bv);
                }
        }
    }
}

// ---------------------------------------------------------------------------
// MFMA flash attention (unchanged from R8): zero-shuffle P path,
// mask-as-accumulator-init, 4 waves x 32 q-rows, KVBLK=64, dbuf stage-early.
// ---------------------------------------------------------------------------
__global__ __launch_bounds__(256) void attn_mfma(
    const bf16_t* __restrict__ qg, const bf16_t* __restrict__ kg,
    const bf16_t* __restrict__ vg, const int* __restrict__ mask,
    bf16_t* __restrict__ ctx)
{
    __shared__ bf16_t ks[2][64 * 64];   // [key][d] 128B rows, fk-swizzled
    __shared__ bf16_t vts[2][64 * 64];  // [d][key] 128B rows, row&7-swizzled
    __shared__ float  mrow[S_];         // f32 additive bias: 0 or -1e9

    const int tid = threadIdx.x;
    const int w   = tid >> 6;
    const int lr  = tid & 15;
    const int lg  = (tid >> 4) & 3;

    const int bid = blockIdx.x;
    const int xcd = bid & 7, kidx = bid >> 3;        // kidx in [0,128)
    const int bh  = xcd * 8 + (kidx >> 4);           // 8 bh per XCD
    const int xq  = kidx & 15;                       // 16 q-blocks of 128
    const int b   = bh >> 4, h = bh & 15;
    const int q0w = xq * 128 + w * 32;               // wave owns 32 q-rows

    for (int i = tid; i < S_; i += 256)
        mrow[i] = mask[b * S_ + i] ? 0.0f : -1.0e9f;

    bf16x8 aq[2][2];
    #pragma unroll
    for (int f = 0; f < 2; ++f) {
        const bf16_t* qp = qg + ((size_t)(b * S_ + q0w + f * 16 + lr) << 10) + h * 64 + lg * 8;
        aq[f][0] = ldsx8(qp);
        aq[f][1] = ldsx8(qp + 32);
    }

    bf16x8 onesf;
    {
        bf16_t o1 = (bf16_t)((lr == 0) ? 1.0f : 0.0f);
        #pragma unroll
        for (int j = 0; j < 8; ++j) onesf[j] = o1;
    }

    int koff[2][2][2], voff[2][4];
    #pragma unroll
    for (int c = 0; c < 2; ++c) {
        #pragma unroll
        for (int kf1 = 0; kf1 < 2; ++kf1) {
            const int row = c * 32 + 8 * (lr >> 2) + 4 * kf1 + (lr & 3);
            const int f = fk(row);
            koff[c][kf1][0] = row * 128 + ((lg ^ f) << 4);
            koff[c][kf1][1] = row * 128 + (((4 + lg) ^ f) << 4);
        }
        #pragma unroll
        for (int n = 0; n < 4; ++n) {
            const int rowv = n * 16 + lr;
            voff[c][n] = rowv * 128 + (((4 * c + lg) ^ (rowv & 7)) << 4);
        }
    }

    const bf16_t* kptr[2];
    const bf16_t* vptr[2];
    char* kdst[2];
    char* vdst[2];
    #pragma unroll
    for (int it = 0; it < 2; ++it) {
        const int idx = it * 256 + tid;
        const int row = idx >> 3, slot = idx & 7;
        kptr[it] = kg + ((size_t)(b * S_ + row) << 10) + h * 64 + (slot ^ fk(row)) * 8;
        vptr[it] = vg + (((size_t)bh * 64 + row) << 11) + (slot ^ (row & 7)) * 8;
        kdst[it] = (char*)ks + idx * 16;
        vdst[it] = (char*)vts + idx * 16;
    }

    f32x4 accO[2][4] = {};
    f32x4 accL[2] = {};

    auto STAGE = [&](int buf) {
        const int nb = buf << 13;
        #pragma unroll
        for (int it = 0; it < 2; ++it) {
            gload_lds16(kptr[it], kdst[it] + nb);
            gload_lds16(vptr[it], vdst[it] + nb);
            kptr[it] += (size_t)64 << 10;
            vptr[it] += 64;
        }
    };

    auto COMPUTE = [&](int buf, int t0) {
        const char* ksb = (const char*)ks + (buf << 13);
        const char* vsb = (const char*)vts + (buf << 13);
        #pragma unroll
        for (int c = 0; c < 2; ++c) {
            unsigned int pw0[4], pw1[4];
            #pragma unroll
            for (int kf1 = 0; kf1 < 2; ++kf1) {
                bf16x8 a0 = ldsx8(ksb + koff[c][kf1][0]);
                bf16x8 a1 = ldsx8(ksb + koff[c][kf1][1]);
                const f32x4 bias = *(const f32x4*)&mrow[t0 + c * 32 + 8 * lg + 4 * kf1];
                f32x4 z0 = bias, z1 = bias;
                __builtin_amdgcn_s_setprio(1);
                z0 = __builtin_amdgcn_mfma_f32_16x16x32_bf16(a0, aq[0][0], z0, 0, 0, 0);
                z0 = __builtin_amdgcn_mfma_f32_16x16x32_bf16(a1, aq[0][1], z0, 0, 0, 0);
                z1 = __builtin_amdgcn_mfma_f32_16x16x32_bf16(a0, aq[1][0], z1, 0, 0, 0);
                z1 = __builtin_amdgcn_mfma_f32_16x16x32_bf16(a1, aq[1][1], z1, 0, 0, 0);
                __builtin_amdgcn_s_setprio(0);
                const float p00 = __builtin_amdgcn_exp2f(z0[0]);
                const float p01 = __builtin_amdgcn_exp2f(z0[1]);
                const float p02 = __builtin_amdgcn_exp2f(z0[2]);
                const float p03 = __builtin_amdgcn_exp2f(z0[3]);
                const float p10 = __builtin_amdgcn_exp2f(z1[0]);
                const float p11 = __builtin_amdgcn_exp2f(z1[1]);
                const float p12 = __builtin_amdgcn_exp2f(z1[2]);
                const float p13 = __builtin_amdgcn_exp2f(z1[3]);
                pw0[2 * kf1]     = bf16bits(p00) | ((unsigned)bf16bits(p01) << 16);
                pw0[2 * kf1 + 1] = bf16bits(p02) | ((unsigned)bf16bits(p03) << 16);
                pw1[2 * kf1]     = bf16bits(p10) | ((unsigned)bf16bits(p11) << 16);
                pw1[2 * kf1 + 1] = bf16bits(p12) | ((unsigned)bf16bits(p13) << 16);
            }
            uint4 pk0 = {pw0[0], pw0[1], pw0[2], pw0[3]};
            uint4 pk1 = {pw1[0], pw1[1], pw1[2], pw1[3]};
            const bf16x8 pa0 = __builtin_bit_cast(bf16x8, pk0);
            const bf16x8 pa1 = __builtin_bit_cast(bf16x8, pk1);

            __builtin_amdgcn_s_setprio(1);
            #pragma unroll
            for (int n = 0; n < 4; ++n) {
                bf16x8 av = ldsx8(vsb + voff[c][n]);
                accO[0][n] = __builtin_amdgcn_mfma_f32_16x16x32_bf16(av, pa0, accO[0][n], 0, 0, 0);
                accO[1][n] = __builtin_amdgcn_mfma_f32_16x16x32_bf16(av, pa1, accO[1][n], 0, 0, 0);
            }
            accL[0] = __builtin_amdgcn_mfma_f32_16x16x32_bf16(onesf, pa0, accL[0], 0, 0, 0);
            accL[1] = __builtin_amdgcn_mfma_f32_16x16x32_bf16(onesf, pa1, accL[1], 0, 0, 0);
            __builtin_amdgcn_s_setprio(0);
        }
    };

    STAGE(0);
    __syncthreads();

    for (int t0 = 0; t0 < S_; t0 += 128) {
        STAGE(1);
        COMPUTE(0, t0);
        __syncthreads();
        if (t0 + 128 < S_) STAGE(0);
        COMPUTE(1, t0 + 64);
        __syncthreads();
    }

    #pragma unroll
    for (int f = 0; f < 2; ++f) {
        const float inv = 1.0f / __shfl(accL[f][0], lr);
        bf16_t* obase = ctx + ((size_t)(b * S_ + q0w + f * 16 + lr) << 10) + h * 64;
        #pragma unroll
        for (int n = 0; n < 4; ++n) {
            ushort4 o;
            o.x = bf16bits(accO[f][n][0] * inv);
            o.y = bf16bits(accO[f][n][1] * inv);
            o.z = bf16bits(accO[f][n][2] * inv);
            o.w = bf16bits(accO[f][n][3] * inv);
            *(ushort4*)(obase + n * 16 + lg * 4) = o;
        }
    }
}

// ---------------------------------------------------------------------------
// Fused prep: x cast + weight transpose/converts (+ g1 folded into W1) +
// cs[n]=sum_k g1[k]W1[k][n], bb[n]=sum_k b1[k]W1[k][n] + c1[n]. One launch.
// ---------------------------------------------------------------------------
__global__ __launch_bounds__(256) void prep_all(
    const float* __restrict__ x, bf16_t* __restrict__ xb,
    const float* __restrict__ Wq, const float* __restrict__ Wk,
    const float* __restrict__ Wv, bf16_t* __restrict__ WqkvT,
    const float* __restrict__ Wo, bf16_t* __restrict__ WoT,
    const float* __restrict__ W1, bf16_t* __restrict__ W1gT,
    const float* __restrict__ W2, bf16_t* __restrict__ W2T,
    const float* __restrict__ g1, const float* __restrict__ b1,
    const float* __restrict__ c1,
    float* __restrict__ csv, float* __restrict__ bbv)
{
    __shared__ float t[32][33];
    __shared__ float red[2][4][64];
    const int tid = threadIdx.x;
    int bid = blockIdx.x;

    if (bid < 4096) {               // x f32 -> bf16, 8 per thread
        int i = bid * 256 + tid;
        float4 a = ((const float4*)x)[i * 2];
        float4 b = ((const float4*)x)[i * 2 + 1];
        unsigned int p0 = bf16bits(a.x) | ((unsigned)bf16bits(a.y) << 16);
        unsigned int p1 = bf16bits(a.z) | ((unsigned)bf16bits(a.w) << 16);
        unsigned int p2 = bf16bits(b.x) | ((unsigned)bf16bits(b.y) << 16);
        unsigned int p3 = bf16bits(b.z) | ((unsigned)bf16bits(b.w) << 16);
        uint4 o = {p0, p1, p2, p3};
        ((uint4*)xb)[i] = o;
        return;
    }
    bid -= 4096;

    if (bid == 4224) {              // cs / bb reduction (single block)
        const int n = tid & 63, part = tid >> 6;
        float csp = 0.0f, bbp = 0.0f;
        for (int k = part * 256; k < part * 256 + 256; ++k) {
            const float wv = W1[k * 64 + n];
            csp += g1[k] * wv;
            bbp += b1[k] * wv;
        }
        red[0][part][n] = csp;
        red[1][part][n] = bbp;
        __syncthreads();
        if (tid < 64) {
            csv[tid] = red[0][0][tid] + red[0][1][tid] + red[0][2][tid] + red[0][3][tid];
            bbv[tid] = red[1][0][tid] + red[1][1][tid] + red[1][2][tid] + red[1][3][tid]
                       + c1[tid];
        }
        return;
    }

    const float* in; bf16_t* out;
    const float* gvec = nullptr;
    int R, C, c0, r0;
    float scale = 1.0f;
    if (bid < 3072) {               // Wq/Wk/Wv [16][1024][64] -> per-head [64][1024]
        const int p = bid >> 10, r = bid & 1023;
        const int z = r >> 6, rem = r & 63;
        in  = (p == 0 ? Wq : p == 1 ? Wk : Wv) + z * 65536;
        out = WqkvT + p * 1048576 + z * 65536;
        R = 1024; C = 64;
        c0 = (rem & 1) * 32; r0 = (rem >> 1) * 32;
        if (p == 0) scale = QSCALE;
    } else if (bid < 4096) {        // Wo [1024][1024]
        const int r = bid - 3072;
        in = Wo; out = WoT; R = 1024; C = 1024;
        c0 = (r & 31) * 32; r0 = (r >> 5) * 32;
    } else if (bid < 4160) {        // W1 [1024][64], g1 folded per row k
        const int r = bid - 4096;
        in = W1; out = W1gT; R = 1024; C = 64;
        c0 = (r & 1) * 32; r0 = (r >> 1) * 32;
        gvec = g1;
    } else {                        // W2 [64][1024]
        const int r = bid - 4160;
        in = W2; out = W2T; R = 64; C = 1024;
        c0 = (r & 31) * 32; r0 = (r >> 5) * 32;
    }

    {
        int rr = tid >> 3, c4 = (tid & 7) * 4;
        float sc = gvec ? gvec[r0 + rr] : scale;
        float4 v = *(const float4*)&in[(size_t)(r0 + rr) * C + c0 + c4];
        t[rr][c4 + 0] = v.x * sc;
        t[rr][c4 + 1] = v.y * sc;
        t[rr][c4 + 2] = v.z * sc;
        t[rr][c4 + 3] = v.w * sc;
    }
    __syncthreads();
    {
        int c = tid >> 3, r4 = (tid & 7) * 4;
        ushort4 o;
        o.x = bf16bits(t[r4 + 0][c]);
        o.y = bf16bits(t[r4 + 1][c]);
        o.z = bf16bits(t[r4 + 2][c]);
        o.w = bf16bits(t[r4 + 3][c]);
        *(ushort4*)(out + (size_t)(c0 + c) * R + r0 + r4) = o;
    }
}

// ---------------------------------------------------------------------------
// Row stats for fused LN1: mean + rstd over 1024 bf16. One row per block.
// ---------------------------------------------------------------------------
__global__ __launch_bounds__(256) void ln_stats(
    const bf16_t* __restrict__ in, float* __restrict__ mv, float* __restrict__ rv)
{
    const int row = blockIdx.x;
    const int tid = threadIdx.x;
    ushort4 xv = *(const ushort4*)(in + (size_t)row * E_ + tid * 4);
    float x0 = (float)__builtin_bit_cast(bf16_t, xv.x);
    float x1 = (float)__builtin_bit_cast(bf16_t, xv.y);
    float x2 = (float)__builtin_bit_cast(bf16_t, xv.z);
    float x3 = (float)__builtin_bit_cast(bf16_t, xv.w);
    float s  = x0 + x1 + x2 + x3;
    float sq = x0 * x0 + x1 * x1 + x2 * x2 + x3 * x3;
    #pragma unroll
    for (int off = 32; off > 0; off >>= 1) {
        s  += __shfl_down(s, off);
        sq += __shfl_down(sq, off);
    }
    __shared__ float ss[4], ssq[4];
    if ((tid & 63) == 0) { ss[tid >> 6] = s; ssq[tid >> 6] = sq; }
    __syncthreads();
    if (tid == 0) {
        s  = ss[0] + ss[1] + ss[2] + ss[3];
        sq = ssq[0] + ssq[1] + ssq[2] + ssq[3];
        const float mean = s * (1.0f / E_);
        const float var  = sq * (1.0f / E_) - mean * mean;
        mv[row] = mean;
        rv[row] = rsqrtf(var + 1e-5f);
    }
}

// ---------------------------------------------------------------------------
// Fused LN1+FFN1+GELU+FFN2: per block of 32 rows:
//  phase 1: G = t1b[32xK] x W1gT[64xK]^T (BK=64, dbuf);
//           u = rstd*(G - m*cs) + bb; f1 = gelu(u) -> LDS [32][64]
//  phase 2: f2 = f1 x W2T^T + c2, streaming W2T in 8 chunks of 128 cols (dbuf)
// 4 waves; LDS 40KB.
// ---------------------------------------------------------------------------
__global__ __launch_bounds__(256) void ffn_fused(
    const bf16_t* __restrict__ t1b, const bf16_t* __restrict__ W1gT,
    const bf16_t* __restrict__ W2T,
    const float* __restrict__ mv, const float* __restrict__ rv,
    const float* __restrict__ csv, const float* __restrict__ bbv,
    const float* __restrict__ c2, bf16_t* __restrict__ f2b)
{
    __shared__ char lds[40960];
    // phase 1: As dbuf @0/@12288 (4KB each), Bs dbuf @4096/@16384 (8KB each)
    // f1s @36864 (4KB). phase 2: Bs2 dbuf @0/@16384 (16KB each).
    const int tid = threadIdx.x;
    const int w   = tid >> 6;
    const int wr  = w >> 1, wc = w & 1;
    const int lr  = tid & 15;
    const int lg  = (tid >> 4) & 3;
    const int bm  = blockIdx.x * 32;

    // ---------------- phase 1 ----------------
    f32x4 acc[2] = {};

    auto STAGE1 = [&](int buf, int kk) {
        char* As = lds + buf * 12288;
        char* Bs = lds + 4096 + buf * 12288;
        {   // A: 32 rows x 64 -> 1 gload/thread
            int row = tid >> 3, slot = tid & 7;
            gload_lds16(t1b + (size_t)(bm + row) * 1024 + kk + (slot ^ (row & 7)) * 8,
                        As + tid * 16);
        }
        #pragma unroll
        for (int i = 0; i < 2; ++i) {   // B: 64 rows x 64 -> 2 gloads/thread
            int idx = i * 256 + tid;
            int row = idx >> 3, slot = idx & 7;
            gload_lds16(W1gT + (size_t)row * 1024 + kk + (slot ^ (row & 7)) * 8,
                        Bs + idx * 16);
        }
    };
    auto COMPUTE1 = [&](int buf) {
        const char* As = lds + buf * 12288;
        const char* Bs = lds + 4096 + buf * 12288;
        #pragma unroll
        for (int h = 0; h < 2; ++h) {
            const int row = wr * 16 + lr;
            bf16x8 af = ldsx8(As + row * 128 + (((4 * h + lg) ^ (row & 7)) << 4));
            #pragma unroll
            for (int n = 0; n < 2; ++n) {
                const int col = wc * 32 + n * 16 + lr;
                bf16x8 bfr = ldsx8(Bs + col * 128 + (((4 * h + lg) ^ (col & 7)) << 4));
                acc[n] = __builtin_amdgcn_mfma_f32_16x16x32_bf16(af, bfr, acc[n], 0, 0, 0);
            }
        }
    };

    STAGE1(0, 0);
    __syncthreads();
    for (int kk = 0; kk < 1024; kk += 64) {
        const int buf = (kk >> 6) & 1;
        if (kk + 64 < 1024) STAGE1(buf ^ 1, kk + 64);
        COMPUTE1(buf);
        __syncthreads();
    }

    // epilogue phase 1: LN-affine + GELU -> f1s
    {
        float mr[4], rr_[4];
        #pragma unroll
        for (int r = 0; r < 4; ++r) {
            const int grow = bm + wr * 16 + lg * 4 + r;
            mr[r]  = mv[grow];
            rr_[r] = rv[grow];
        }
        char* f1s = lds + 36864;
        #pragma unroll
        for (int n = 0; n < 2; ++n) {
            const int col = wc * 32 + n * 16 + lr;
            const float csn = csv[col], bbn = bbv[col];
            #pragma unroll
            for (int r = 0; r < 4; ++r) {
                const int rowl = wr * 16 + lg * 4 + r;
                float u = rr_[r] * (acc[n][r] - mr[r] * csn) + bbn;
                u = 0.5f * u * (1.0f + erff(u * 0.70710678118654752f));
                *(bf16_t*)(f1s + rowl * 128 + (((col >> 3) ^ (rowl & 7)) << 4)
                           + (col & 7) * 2) = (bf16_t)u;
            }
        }
    }
    __syncthreads();    // f1s visible; phase-1 buffers dead

    // ---------------- phase 2 ----------------
    auto STAGE2 = [&](int buf, int cn) {
        char* Bs2 = lds + buf * 16384;
        #pragma unroll
        for (int i = 0; i < 4; ++i) {   // 128 rows x 64 -> 4 gloads/thread
            int idx = i * 256 + tid;
            int row = idx >> 3, slot = idx & 7;
            gload_lds16(W2T + (size_t)(cn * 128 + row) * 64 + (slot ^ (row & 7)) * 8,
                        Bs2 + idx * 16);
        }
    };

    // A-frags from f1s (constant across chunks): row = wr*16+lr, k = h*32+lg*8
    bf16x8 af2[2];
    {
        const char* f1s = lds + 36864;
        const int row = wr * 16 + lr;
        af2[0] = ldsx8(f1s + row * 128 + ((lg ^ (row & 7)) << 4));
        af2[1] = ldsx8(f1s + row * 128 + (((4 + lg) ^ (row & 7)) << 4));
    }

    STAGE2(0, 0);
    __syncthreads();

    for (int cn = 0; cn < 8; ++cn) {
        const int buf = cn & 1;
        if (cn + 1 < 8) STAGE2(buf ^ 1, cn + 1);
        const char* Bs2 = lds + buf * 16384;
        f32x4 acc2[4] = {};
        #pragma unroll
        for (int h = 0; h < 2; ++h) {
            #pragma unroll
            for (int n = 0; n < 4; ++n) {
                const int col = wc * 64 + n * 16 + lr;
                bf16x8 bfr = ldsx8(Bs2 + col * 128 + (((4 * h + lg) ^ (col & 7)) << 4));
                acc2[n] = __builtin_amdgcn_mfma_f32_16x16x32_bf16(af2[h], bfr, acc2[n], 0, 0, 0);
            }
        }
        #pragma unroll
        for (int n = 0; n < 4; ++n) {
            const int gcol = cn * 128 + wc * 64 + n * 16 + lr;
            const float bv = c2[gcol];
            #pragma unroll
            for (int r = 0; r < 4; ++r) {
                const int grow = bm + wr * 16 + lg * 4 + r;
                f2b[(size_t)grow * 1024 + gcol] = (bf16_t)(acc2[n][r] + bv);
            }
        }
        __syncthreads();
    }
}

// ---------------------------------------------------------------------------
// Row LayerNorm over 1024, bf16 in, f32 out (final).
// ---------------------------------------------------------------------------
__global__ __launch_bounds__(256) void ln_kernel(
    const bf16_t* __restrict__ in, const float* __restrict__ g,
    const float* __restrict__ bta, float* __restrict__ out)
{
    const int row = blockIdx.x;
    const int tid = threadIdx.x;

    ushort4 xv = *(const ushort4*)(in + (size_t)row * E_ + tid * 4);
    float x0 = (float)__builtin_bit_cast(bf16_t, xv.x);
    float x1 = (float)__builtin_bit_cast(bf16_t, xv.y);
    float x2 = (float)__builtin_bit_cast(bf16_t, xv.z);
    float x3 = (float)__builtin_bit_cast(bf16_t, xv.w);
    float s  = x0 + x1 + x2 + x3;
    float sq = x0 * x0 + x1 * x1 + x2 * x2 + x3 * x3;
    #pragma unroll
    for (int off = 32; off > 0; off >>= 1) {
        s  += __shfl_down(s, off);
        sq += __shfl_down(sq, off);
    }
    __shared__ float ss[4], ssq[4];
    if ((tid & 63) == 0) { ss[tid >> 6] = s; ssq[tid >> 6] = sq; }
    __syncthreads();
    s  = ss[0] + ss[1] + ss[2] + ss[3];
    sq = ssq[0] + ssq[1] + ssq[2] + ssq[3];

    const float mean = s * (1.0f / E_);
    const float var  = sq * (1.0f / E_) - mean * mean;
    const float rstd = rsqrtf(var + 1e-5f);

    float4 gv = ((const float4*)g)[tid];
    float4 bv = ((const float4*)bta)[tid];
    float4 o;
    o.x = (x0 - mean) * rstd * gv.x + bv.x;
    o.y = (x1 - mean) * rstd * gv.y + bv.y;
    o.z = (x2 - mean) * rstd * gv.z + bv.z;
    o.w = (x3 - mean) * rstd * gv.w + bv.w;
    ((float4*)(out + (size_t)row * E_))[tid] = o;
}

// ---------------------------------------------------------------------------
extern "C" void kernel_launch(void* const* d_in, const int* in_sizes, int n_in,
                              void* d_out, int out_size, void* d_ws, size_t ws_size,
                              hipStream_t stream)
{
    const float* x    = (const float*)d_in[0];
    const int*   mask = (const int*)d_in[1];
    const float* Wq   = (const float*)d_in[2];
    const float* bq   = (const float*)d_in[3];
    const float* Wk   = (const float*)d_in[4];
    const float* bk   = (const float*)d_in[5];
    const float* Wv   = (const float*)d_in[6];
    const float* bv   = (const float*)d_in[7];
    const float* Wo   = (const float*)d_in[8];
    const float* bo   = (const float*)d_in[9];
    const float* g1   = (const float*)d_in[10];
    const float* b1   = (const float*)d_in[11];
    const float* W1   = (const float*)d_in[12];
    const float* c1   = (const float*)d_in[13];
    const float* W2   = (const float*)d_in[14];
    const float* c2   = (const float*)d_in[15];
    const float* g2   = (const float*)d_in[16];
    const float* b2   = (const float*)d_in[17];

    char* W = (char*)d_ws;                       // peak ~92.7 MB
    bf16_t* xb    = (bf16_t*)(W + 0);            // 16 MB
    bf16_t* WqkvT = (bf16_t*)(W + 16777216);     //  6 MB [3][1024 n][1024 k]
    bf16_t* WoT   = (bf16_t*)(W + 23068672);     //  2 MB
    bf16_t* W1gT  = (bf16_t*)(W + 25165824);     //  128K [64][1024]
    bf16_t* W2T   = (bf16_t*)(W + 25296896);     //  128K [1024][64]
    bf16_t* qbuf  = (bf16_t*)(W + 25427968);     // 16 MB [b,s,h,d]
    bf16_t* kbuf  = (bf16_t*)(W + 42205184);     // 16 MB [b,s,h,d]
    bf16_t* vtb   = (bf16_t*)(W + 58982400);     // 16 MB [bh][d][s] (direct)
    bf16_t* ctx   = (bf16_t*)(W + 75759616);     // 16 MB
    bf16_t* t1b   = (bf16_t*)(W + 25427968);     // 16 MB over qbuf (dead)
    bf16_t* f2b   = (bf16_t*)(W + 75759616);     // over ctx (dead)
    float*  mv    = (float*)(W + 92536832);      // 32 KB
    float*  rv    = (float*)(W + 92569600);      // 32 KB
    float*  csv   = (float*)(W + 92602368);      // 256 B
    float*  bbv   = (float*)(W + 92602624);      // 256 B
    float*  out   = (float*)d_out;

    // fused prep (1/sqrt(S)*log2e into Wq; g1 into W1; cs/bb vectors)
    prep_all<<<8321, 256, 0, stream>>>(x, xb, Wq, Wk, Wv, WqkvT,
                                       Wo, WoT, W1, W1gT, W2, W2T,
                                       g1, b1, c1, csv, bbv);

    // fused QKV projection [8192 x 3072 x 1024]; V written pre-transposed
    gemm_bf16<128, 128, 2><<<dim3(24, 64), 256, 0, stream>>>(
        xb, WqkvT, qbuf, kbuf, vtb, bq, bk, bv, M_, 3072, 1024);

    attn_mfma<<<dim3(1024), 256, 0, stream>>>(qbuf, kbuf, vtb, mask, ctx);

    // output projection -> bf16 t1
    gemm_bf16<128, 128, 0><<<dim3(8, 64), 256, 0, stream>>>(
        ctx, WoT, t1b, nullptr, nullptr, bo, nullptr, nullptr, M_, 1024, 1024);

    // LN1 stats (mean / rstd per row of t1b)
    ln_stats<<<8192, 256, 0, stream>>>(t1b, mv, rv);

    // fused LN1 + FFN1 + GELU + FFN2 -> f2b
    ffn_fused<<<256, 256, 0, stream>>>(t1b, W1gT, W2T, mv, rv, csv, bbv, c2, f2b);

    ln_kernel<<<8192, 256, 0, stream>>>(f2b, g2, b2, out);
}

// Round 10
// 234.145 us; speedup vs baseline: 1.0282x; 1.0282x over previous
//
#include <hip/hip_runtime.h>
#include <math.h>

#define B_ 4
#define S_ 2048
#define E_ 1024
#define H_ 16
#define D_ 64
#define M_ (B_*S_)
// 1/sqrt(2048) * log2(e): scale folded into Wq/bq so softmax uses exp2 directly
#define QSCALE (0.022097086912079608f * 1.4426950408889634f)

typedef __bf16 bf16_t;
typedef __bf16 bf16x8 __attribute__((ext_vector_type(8)));
typedef float  f32x4  __attribute__((ext_vector_type(4)));

// async global->LDS, 16B per lane. LDS dest must be linear (base + lane*16).
__device__ __forceinline__ void gload_lds16(const void* g, void* l) {
    __builtin_amdgcn_global_load_lds(
        (const __attribute__((address_space(1))) void*)g,
        (__attribute__((address_space(3))) void*)l, 16, 0, 0);
}
__device__ __forceinline__ bf16x8 ldsx8(const void* p) {
    return __builtin_bit_cast(bf16x8, *(const uint4*)p);
}
__device__ __forceinline__ unsigned short bf16bits(float x) {
    return __builtin_bit_cast(unsigned short, (bf16_t)x);
}
// swizzle for K-tile QK^T A-frag read rows {32c + 8a + 4kf + b}: f = (b + 2a) & 7
__device__ __forceinline__ int fk(int row) { return ((row & 3) + 2 * ((row >> 3) & 3)) & 7; }

// ---------------------------------------------------------------------------
// bf16 MFMA GEMM, C = A[M,K] x Bt[N,K]^T. BK=64, 4 waves, wave tile (BM/2)x(BN/2).
// Grid flattened + bijective XCD swizzle (requires nwg % 8 == 0).
// MODE 0: bf16 out + bias. MODE 1: bf16 out + bias + exact GELU.
// MODE 2: QKV scatter; Q bias scaled by QSCALE; K rows and V^T columns written
//         compacted via cidx (masked keys dropped); V as vt[bh][d][s_c].
// ---------------------------------------------------------------------------
template<int BM, int BN, int MODE>
__global__ __launch_bounds__(256) void gemm_bf16(
    const bf16_t* __restrict__ A, const bf16_t* __restrict__ Bt,
    bf16_t* __restrict__ ob0, bf16_t* __restrict__ ob1, bf16_t* __restrict__ ob2,
    const float* __restrict__ bias0, const float* __restrict__ bias1,
    const float* __restrict__ bias2, const int* __restrict__ cidx,
    int M, int N, int K)
{
    constexpr int FM = BM / 32, FN = BN / 32;
    __shared__ bf16_t As[BM * 64];
    __shared__ bf16_t Bs[BN * 64];

    const int tid = threadIdx.x;
    const int w   = tid >> 6;
    const int wr  = w >> 1, wc = w & 1;
    const int lr  = tid & 15;
    const int lg  = (tid >> 4) & 3;

    // XCD-bijective block swizzle: 8 contiguous chunks, one per XCD
    const int nwg  = gridDim.x * gridDim.y;
    int bidf = blockIdx.y * gridDim.x + blockIdx.x;
    bidf = (bidf & 7) * (nwg >> 3) + (bidf >> 3);
    const int bm = (bidf / gridDim.x) * BM;
    const int bn = (bidf % gridDim.x) * BN;

    f32x4 acc[FM][FN] = {};

    for (int kk = 0; kk < K; kk += 64) {
        __syncthreads();
        #pragma unroll
        for (int i = 0; i < BM / 32; ++i) {
            int idx = i * 256 + tid;
            int row = idx >> 3, slot = idx & 7;
            gload_lds16(A + (size_t)(bm + row) * K + kk + (slot ^ (row & 7)) * 8,
                        (char*)As + idx * 16);
        }
        #pragma unroll
        for (int i = 0; i < BN / 32; ++i) {
            int idx = i * 256 + tid;
            int row = idx >> 3, slot = idx & 7;
            gload_lds16(Bt + (size_t)(bn + row) * K + kk + (slot ^ (row & 7)) * 8,
                        (char*)Bs + idx * 16);
        }
        __syncthreads();

        #pragma unroll
        for (int h = 0; h < 2; ++h) {
            bf16x8 af[FM], bfr[FN];
            #pragma unroll
            for (int m = 0; m < FM; ++m) {
                int row = wr * (BM / 2) + m * 16 + lr;
                af[m] = ldsx8((char*)As + row * 128 + (((4 * h + lg) ^ (row & 7)) << 4));
            }
            #pragma unroll
            for (int n = 0; n < FN; ++n) {
                int col = wc * (BN / 2) + n * 16 + lr;
                bfr[n] = ldsx8((char*)Bs + col * 128 + (((4 * h + lg) ^ (col & 7)) << 4));
            }
            #pragma unroll
            for (int m = 0; m < FM; ++m)
                #pragma unroll
                for (int n = 0; n < FN; ++n)
                    acc[m][n] = __builtin_amdgcn_mfma_f32_16x16x32_bf16(
                        af[m], bfr[n], acc[m][n], 0, 0, 0);
        }
    }

    #pragma unroll
    for (int n = 0; n < FN; ++n) {
        const int gcol = bn + wc * (BN / 2) + n * 16 + lr;
        if constexpr (MODE == 2) {
            const int p = gcol >> 10, nn = gcol & 1023;
            const float bv = (p == 0) ? bias0[nn] * QSCALE
                           : (p == 1) ? bias1[nn] : bias2[nn];
            #pragma unroll
            for (int m = 0; m < FM; ++m) {
                const int grow0 = bm + wr * (BM / 2) + m * 16 + lg * 4;
                const int bb = grow0 >> 11;
                if (p == 0) {
                    #pragma unroll
                    for (int r = 0; r < 4; ++r)
                        ob0[((size_t)(grow0 + r) << 10) + nn] = (bf16_t)(acc[m][n][r] + bv);
                } else if (p == 1) {
                    #pragma unroll
                    for (int r = 0; r < 4; ++r) {
                        const int ci = cidx[(bb << 11) + ((grow0 + r) & 2047)];
                        if (ci >= 0)
                            ob1[(((size_t)(bb << 11) + ci) << 10) + nn] =
                                (bf16_t)(acc[m][n][r] + bv);
                    }
                } else {
                    #pragma unroll
                    for (int r = 0; r < 4; ++r) {
                        const int ci = cidx[(bb << 11) + ((grow0 + r) & 2047)];
                        if (ci >= 0)
                            ob2[((((size_t)bb << 10) + nn) << 11) + ci] =
                                (bf16_t)(acc[m][n][r] + bv);
                    }
                }
            }
        } else {
            const float bv = bias0[gcol];
            #pragma unroll
            for (int m = 0; m < FM; ++m)
                #pragma unroll
                for (int r = 0; r < 4; ++r) {
                    const int grow = bm + wr * (BM / 2) + m * 16 + lg * 4 + r;
                    float v = acc[m][n][r] + bv;
                    if constexpr (MODE == 1)
                        v = 0.5f * v * (1.0f + erff(v * 0.70710678118654752f));
                    ob0[(size_t)grow * N + gcol] = (bf16_t)v;
                }
        }
    }
}

// ---------------------------------------------------------------------------
// Mask compaction: order-preserving prefix scan of mask[b][:] -> cidx (or -1),
// nkv[b] = survivor count. Also zeroes pad rows of compact K and pad columns
// of compact V^T up to the next multiple of 64 (so z = -1e9 exactly, p = 0).
// grid 4 (one per b), 256 threads.
// ---------------------------------------------------------------------------
__global__ __launch_bounds__(256) void compact_mask(
    const int* __restrict__ mask, int* __restrict__ cidx,
    int* __restrict__ nkv, bf16_t* __restrict__ kc, bf16_t* __restrict__ vtc)
{
    __shared__ int wsum[4];
    const int b = blockIdx.x;
    const int tid = threadIdx.x;
    const int lane = tid & 63, wv = tid >> 6;
    const int base = tid * 8;

    int m[8], loc[8];
    int cnt = 0;
    #pragma unroll
    for (int j = 0; j < 8; ++j) {
        m[j] = mask[b * S_ + base + j];
        loc[j] = cnt;
        cnt += (m[j] != 0);
    }
    // wave inclusive scan
    int incl = cnt;
    #pragma unroll
    for (int off = 1; off < 64; off <<= 1) {
        int t = __shfl_up(incl, off);
        if (lane >= off) incl += t;
    }
    if (lane == 63) wsum[wv] = incl;
    const int excl_lane = incl - cnt;
    __syncthreads();
    int wbase = 0;
    for (int i = 0; i < wv; ++i) wbase += wsum[i];
    const int total = wsum[0] + wsum[1] + wsum[2] + wsum[3];
    if (tid == 0) nkv[b] = total;
    const int tbase = wbase + excl_lane;
    #pragma unroll
    for (int j = 0; j < 8; ++j)
        cidx[b * S_ + base + j] = m[j] ? (tbase + loc[j]) : -1;

    // zero pad regions [nk, nkp)
    const int nk = total, nkp = (total + 63) & ~63;
    // K rows: kc[((b<<11)+r)<<10 .. +1024), bf16 -> 512 dwords
    for (int r = nk + wv; r < nkp; r += 4) {
        unsigned int* dst = (unsigned int*)(kc + (((size_t)(b << 11) + r) << 10));
        for (int c = lane; c < 512; c += 64) dst[c] = 0u;
    }
    // V^T columns: rows b*1024..b*1024+1023, cols [nk, nkp)
    for (int rr = tid; rr < 1024; rr += 256) {
        bf16_t* dst = vtc + (((size_t)(b << 10) + rr) << 11);
        for (int c = nk; c < nkp; ++c) dst[c] = (bf16_t)0.0f;
    }
}

// ---------------------------------------------------------------------------
// MFMA flash attention over COMPACTED keys (masked keys dropped; exact).
// Zero-shuffle P path, 4 waves x 32 q-rows = QBLK 128, KVBLK=64,
// double-buffered stage-early. Full tiles: z init = 0 (no mask op at all).
// Straddling tile: 4-compare register bias (keyb+r < nk ? 0 : -1e9).
// L via ones-row MFMA; exp2-domain scores. 8 bh per XCD for K/V L2 locality.
// ---------------------------------------------------------------------------
__global__ __launch_bounds__(256) void attn_mfma(
    const bf16_t* __restrict__ qg, const bf16_t* __restrict__ kg,
    const bf16_t* __restrict__ vg, const int* __restrict__ nkv,
    bf16_t* __restrict__ ctx)
{
    __shared__ bf16_t ks[2][64 * 64];   // [key][d] 128B rows, fk-swizzled
    __shared__ bf16_t vts[2][64 * 64];  // [d][key] 128B rows, row&7-swizzled

    const int tid = threadIdx.x;
    const int w   = tid >> 6;
    const int lr  = tid & 15;
    const int lg  = (tid >> 4) & 3;

    const int bid = blockIdx.x;
    const int xcd = bid & 7, kidx = bid >> 3;        // kidx in [0,128)
    const int bh  = xcd * 8 + (kidx >> 4);           // 8 bh per XCD
    const int xq  = kidx & 15;                       // 16 q-blocks of 128
    const int b   = bh >> 4, h = bh & 15;
    const int q0w = xq * 128 + w * 32;               // wave owns 32 q-rows

    const int nk = nkv[b];
    const int ntiles = (nk + 63) >> 6;
    const bool hastail = (nk & 63) != 0;

    bf16x8 aq[2][2];
    #pragma unroll
    for (int f = 0; f < 2; ++f) {
        const bf16_t* qp = qg + ((size_t)(b * S_ + q0w + f * 16 + lr) << 10) + h * 64 + lg * 8;
        aq[f][0] = ldsx8(qp);
        aq[f][1] = ldsx8(qp + 32);
    }

    bf16x8 onesf;
    {
        bf16_t o1 = (bf16_t)((lr == 0) ? 1.0f : 0.0f);
        #pragma unroll
        for (int j = 0; j < 8; ++j) onesf[j] = o1;
    }

    int koff[2][2][2], voff[2][4];
    #pragma unroll
    for (int c = 0; c < 2; ++c) {
        #pragma unroll
        for (int kf1 = 0; kf1 < 2; ++kf1) {
            const int row = c * 32 + 8 * (lr >> 2) + 4 * kf1 + (lr & 3);
            const int f = fk(row);
            koff[c][kf1][0] = row * 128 + ((lg ^ f) << 4);
            koff[c][kf1][1] = row * 128 + (((4 + lg) ^ f) << 4);
        }
        #pragma unroll
        for (int n = 0; n < 4; ++n) {
            const int rowv = n * 16 + lr;
            voff[c][n] = rowv * 128 + (((4 * c + lg) ^ (rowv & 7)) << 4);
        }
    }

    const bf16_t* kptr[2];
    const bf16_t* vptr[2];
    char* kdst[2];
    char* vdst[2];
    #pragma unroll
    for (int it = 0; it < 2; ++it) {
        const int idx = it * 256 + tid;
        const int row = idx >> 3, slot = idx & 7;
        kptr[it] = kg + ((size_t)((b << 11) + row) << 10) + h * 64 + (slot ^ fk(row)) * 8;
        vptr[it] = vg + (((size_t)bh * 64 + row) << 11) + (slot ^ (row & 7)) * 8;
        kdst[it] = (char*)ks + idx * 16;
        vdst[it] = (char*)vts + idx * 16;
    }

    f32x4 accO[2][4] = {};
    f32x4 accL[2] = {};

    auto STAGE = [&](int buf) {
        const int nb = buf << 13;
        #pragma unroll
        for (int it = 0; it < 2; ++it) {
            gload_lds16(kptr[it], kdst[it] + nb);
            gload_lds16(vptr[it], vdst[it] + nb);
            kptr[it] += (size_t)64 << 10;
            vptr[it] += 64;
        }
    };

    auto COMPUTE = [&](int buf, int t0, bool tl) {
        const char* ksb = (const char*)ks + (buf << 13);
        const char* vsb = (const char*)vts + (buf << 13);
        #pragma unroll
        for (int c = 0; c < 2; ++c) {
            unsigned int pw0[4], pw1[4];
            #pragma unroll
            for (int kf1 = 0; kf1 < 2; ++kf1) {
                bf16x8 a0 = ldsx8(ksb + koff[c][kf1][0]);
                bf16x8 a1 = ldsx8(ksb + koff[c][kf1][1]);
                f32x4 z0 = {}, z1 = {};
                if (tl) {
                    const int keyb = t0 + c * 32 + 8 * lg + 4 * kf1;
                    f32x4 bias;
                    #pragma unroll
                    for (int r = 0; r < 4; ++r)
                        bias[r] = (keyb + r < nk) ? 0.0f : -1.0e9f;
                    z0 = bias; z1 = bias;
                }
                __builtin_amdgcn_s_setprio(1);
                z0 = __builtin_amdgcn_mfma_f32_16x16x32_bf16(a0, aq[0][0], z0, 0, 0, 0);
                z0 = __builtin_amdgcn_mfma_f32_16x16x32_bf16(a1, aq[0][1], z0, 0, 0, 0);
                z1 = __builtin_amdgcn_mfma_f32_16x16x32_bf16(a0, aq[1][0], z1, 0, 0, 0);
                z1 = __builtin_amdgcn_mfma_f32_16x16x32_bf16(a1, aq[1][1], z1, 0, 0, 0);
                __builtin_amdgcn_s_setprio(0);
                const float p00 = __builtin_amdgcn_exp2f(z0[0]);
                const float p01 = __builtin_amdgcn_exp2f(z0[1]);
                const float p02 = __builtin_amdgcn_exp2f(z0[2]);
                const float p03 = __builtin_amdgcn_exp2f(z0[3]);
                const float p10 = __builtin_amdgcn_exp2f(z1[0]);
                const float p11 = __builtin_amdgcn_exp2f(z1[1]);
                const float p12 = __builtin_amdgcn_exp2f(z1[2]);
                const float p13 = __builtin_amdgcn_exp2f(z1[3]);
                pw0[2 * kf1]     = bf16bits(p00) | ((unsigned)bf16bits(p01) << 16);
                pw0[2 * kf1 + 1] = bf16bits(p02) | ((unsigned)bf16bits(p03) << 16);
                pw1[2 * kf1]     = bf16bits(p10) | ((unsigned)bf16bits(p11) << 16);
                pw1[2 * kf1 + 1] = bf16bits(p12) | ((unsigned)bf16bits(p13) << 16);
            }
            uint4 pk0 = {pw0[0], pw0[1], pw0[2], pw0[3]};
            uint4 pk1 = {pw1[0], pw1[1], pw1[2], pw1[3]};
            const bf16x8 pa0 = __builtin_bit_cast(bf16x8, pk0);
            const bf16x8 pa1 = __builtin_bit_cast(bf16x8, pk1);

            __builtin_amdgcn_s_setprio(1);
            #pragma unroll
            for (int n = 0; n < 4; ++n) {
                bf16x8 av = ldsx8(vsb + voff[c][n]);
                accO[0][n] = __builtin_amdgcn_mfma_f32_16x16x32_bf16(av, pa0, accO[0][n], 0, 0, 0);
                accO[1][n] = __builtin_amdgcn_mfma_f32_16x16x32_bf16(av, pa1, accO[1][n], 0, 0, 0);
            }
            accL[0] = __builtin_amdgcn_mfma_f32_16x16x32_bf16(onesf, pa0, accL[0], 0, 0, 0);
            accL[1] = __builtin_amdgcn_mfma_f32_16x16x32_bf16(onesf, pa1, accL[1], 0, 0, 0);
            __builtin_amdgcn_s_setprio(0);
        }
    };

    STAGE(0);
    __syncthreads();

    int cur = 0;
    for (int t = 0; t < ntiles; ++t) {
        if (t + 1 < ntiles) STAGE(cur ^ 1);
        COMPUTE(cur, t * 64, hastail && (t == ntiles - 1));
        __syncthreads();
        cur ^= 1;
    }

    #pragma unroll
    for (int f = 0; f < 2; ++f) {
        const float inv = 1.0f / __shfl(accL[f][0], lr);
        bf16_t* obase = ctx + ((size_t)(b * S_ + q0w + f * 16 + lr) << 10) + h * 64;
        #pragma unroll
        for (int n = 0; n < 4; ++n) {
            ushort4 o;
            o.x = bf16bits(accO[f][n][0] * inv);
            o.y = bf16bits(accO[f][n][1] * inv);
            o.z = bf16bits(accO[f][n][2] * inv);
            o.w = bf16bits(accO[f][n][3] * inv);
            *(ushort4*)(obase + n * 16 + lg * 4) = o;
        }
    }
}

// ---------------------------------------------------------------------------
// Fused prep: x cast + all 5 weight transpose/converts, one launch.
// ---------------------------------------------------------------------------
__global__ __launch_bounds__(256) void prep_all(
    const float* __restrict__ x, bf16_t* __restrict__ xb,
    const float* __restrict__ Wq, const float* __restrict__ Wk,
    const float* __restrict__ Wv, bf16_t* __restrict__ WqkvT,
    const float* __restrict__ Wo, bf16_t* __restrict__ WoT,
    const float* __restrict__ W1, bf16_t* __restrict__ W1T,
    const float* __restrict__ W2, bf16_t* __restrict__ W2T)
{
    __shared__ float t[32][33];
    const int tid = threadIdx.x;
    int bid = blockIdx.x;

    if (bid < 4096) {               // x f32 -> bf16, 8 per thread
        int i = bid * 256 + tid;
        float4 a = ((const float4*)x)[i * 2];
        float4 b = ((const float4*)x)[i * 2 + 1];
        unsigned int p0 = bf16bits(a.x) | ((unsigned)bf16bits(a.y) << 16);
        unsigned int p1 = bf16bits(a.z) | ((unsigned)bf16bits(a.w) << 16);
        unsigned int p2 = bf16bits(b.x) | ((unsigned)bf16bits(b.y) << 16);
        unsigned int p3 = bf16bits(b.z) | ((unsigned)bf16bits(b.w) << 16);
        uint4 o = {p0, p1, p2, p3};
        ((uint4*)xb)[i] = o;
        return;
    }
    bid -= 4096;

    const float* in; bf16_t* out;
    int R, C, c0, r0;
    float scale = 1.0f;
    if (bid < 3072) {               // Wq/Wk/Wv [16][1024][64] -> per-head [64][1024]
        const int p = bid >> 10, r = bid & 1023;
        const int z = r >> 6, rem = r & 63;
        in  = (p == 0 ? Wq : p == 1 ? Wk : Wv) + z * 65536;
        out = WqkvT + p * 1048576 + z * 65536;
        R = 1024; C = 64;
        c0 = (rem & 1) * 32; r0 = (rem >> 1) * 32;
        if (p == 0) scale = QSCALE;
    } else if (bid < 4096) {        // Wo [1024][1024]
        const int r = bid - 3072;
        in = Wo; out = WoT; R = 1024; C = 1024;
        c0 = (r & 31) * 32; r0 = (r >> 5) * 32;
    } else if (bid < 4160) {        // W1 [1024][64]
        const int r = bid - 4096;
        in = W1; out = W1T; R = 1024; C = 64;
        c0 = (r & 1) * 32; r0 = (r >> 1) * 32;
    } else {                        // W2 [64][1024]
        const int r = bid - 4160;
        in = W2; out = W2T; R = 64; C = 1024;
        c0 = (r & 31) * 32; r0 = (r >> 5) * 32;
    }

    {
        int rr = tid >> 3, c4 = (tid & 7) * 4;
        float4 v = *(const float4*)&in[(size_t)(r0 + rr) * C + c0 + c4];
        t[rr][c4 + 0] = v.x * scale;
        t[rr][c4 + 1] = v.y * scale;
        t[rr][c4 + 2] = v.z * scale;
        t[rr][c4 + 3] = v.w * scale;
    }
    __syncthreads();
    {
        int c = tid >> 3, r4 = (tid & 7) * 4;
        ushort4 o;
        o.x = bf16bits(t[r4 + 0][c]);
        o.y = bf16bits(t[r4 + 1][c]);
        o.z = bf16bits(t[r4 + 2][c]);
        o.w = bf16bits(t[r4 + 3][c]);
        *(ushort4*)(out + (size_t)(c0 + c) * R + r0 + r4) = o;
    }
}

// ---------------------------------------------------------------------------
// Row LayerNorm over 1024. InT: float or bf16; OutT: float or bf16.
// ---------------------------------------------------------------------------
template<typename InT, typename OutT>
__global__ __launch_bounds__(256) void ln_kernel(
    const InT* __restrict__ in, const float* __restrict__ g,
    const float* __restrict__ bta, OutT* __restrict__ out)
{
    const int row = blockIdx.x;
    const int tid = threadIdx.x;

    float x0, x1, x2, x3;
    if constexpr (sizeof(InT) == 4) {
        float4 xv = ((const float4*)(in + (size_t)row * E_))[tid];
        x0 = xv.x; x1 = xv.y; x2 = xv.z; x3 = xv.w;
    } else {
        ushort4 xv = *(const ushort4*)((const bf16_t*)in + (size_t)row * E_ + tid * 4);
        x0 = (float)__builtin_bit_cast(bf16_t, xv.x);
        x1 = (float)__builtin_bit_cast(bf16_t, xv.y);
        x2 = (float)__builtin_bit_cast(bf16_t, xv.z);
        x3 = (float)__builtin_bit_cast(bf16_t, xv.w);
    }
    float s  = x0 + x1 + x2 + x3;
    float sq = x0 * x0 + x1 * x1 + x2 * x2 + x3 * x3;
    #pragma unroll
    for (int off = 32; off > 0; off >>= 1) {
        s  += __shfl_down(s, off);
        sq += __shfl_down(sq, off);
    }
    __shared__ float ss[4], ssq[4];
    if ((tid & 63) == 0) { ss[tid >> 6] = s; ssq[tid >> 6] = sq; }
    __syncthreads();
    s  = ss[0] + ss[1] + ss[2] + ss[3];
    sq = ssq[0] + ssq[1] + ssq[2] + ssq[3];

    const float mean = s * (1.0f / E_);
    const float var  = sq * (1.0f / E_) - mean * mean;
    const float rstd = rsqrtf(var + 1e-5f);

    float4 gv = ((const float4*)g)[tid];
    float4 bv = ((const float4*)bta)[tid];
    float o0 = (x0 - mean) * rstd * gv.x + bv.x;
    float o1 = (x1 - mean) * rstd * gv.y + bv.y;
    float o2 = (x2 - mean) * rstd * gv.z + bv.z;
    float o3 = (x3 - mean) * rstd * gv.w + bv.w;
    if constexpr (sizeof(OutT) == 4) {
        float4 o = {o0, o1, o2, o3};
        ((float4*)((float*)out + (size_t)row * E_))[tid] = o;
    } else {
        ushort4 o;
        o.x = bf16bits(o0); o.y = bf16bits(o1);
        o.z = bf16bits(o2); o.w = bf16bits(o3);
        *(ushort4*)((bf16_t*)out + (size_t)row * E_ + tid * 4) = o;
    }
}

// ---------------------------------------------------------------------------
extern "C" void kernel_launch(void* const* d_in, const int* in_sizes, int n_in,
                              void* d_out, int out_size, void* d_ws, size_t ws_size,
                              hipStream_t stream)
{
    const float* x    = (const float*)d_in[0];
    const int*   mask = (const int*)d_in[1];
    const float* Wq   = (const float*)d_in[2];
    const float* bq   = (const float*)d_in[3];
    const float* Wk   = (const float*)d_in[4];
    const float* bk   = (const float*)d_in[5];
    const float* Wv   = (const float*)d_in[6];
    const float* bv   = (const float*)d_in[7];
    const float* Wo   = (const float*)d_in[8];
    const float* bo   = (const float*)d_in[9];
    const float* g1   = (const float*)d_in[10];
    const float* b1   = (const float*)d_in[11];
    const float* W1   = (const float*)d_in[12];
    const float* c1   = (const float*)d_in[13];
    const float* W2   = (const float*)d_in[14];
    const float* c2   = (const float*)d_in[15];
    const float* g2   = (const float*)d_in[16];
    const float* b2   = (const float*)d_in[17];

    char* W = (char*)d_ws;                       // peak ~92.7 MB
    bf16_t* xb    = (bf16_t*)(W + 0);            // 16 MB
    bf16_t* WqkvT = (bf16_t*)(W + 16777216);     //  6 MB [3][1024 n][1024 k]
    bf16_t* WoT   = (bf16_t*)(W + 23068672);     //  2 MB
    bf16_t* W1T   = (bf16_t*)(W + 25165824);     //  128K
    bf16_t* W2T   = (bf16_t*)(W + 25296896);     //  128K
    bf16_t* qbuf  = (bf16_t*)(W + 25427968);     // 16 MB [b,s,h,d]
    bf16_t* kbuf  = (bf16_t*)(W + 42205184);     // 16 MB [b,s_c,h,d] compacted
    bf16_t* vtb   = (bf16_t*)(W + 58982400);     // 16 MB [bh][d][s_c] compacted
    bf16_t* ctx   = (bf16_t*)(W + 75759616);     // 16 MB
    bf16_t* t1b   = (bf16_t*)(W + 25427968);     // 16 MB over qbuf (dead)
    bf16_t* hb    = (bf16_t*)(W + 58982400);     // over vtb (dead)
    bf16_t* f1b   = (bf16_t*)(W + 0);            // over xb (dead)
    bf16_t* f2b   = (bf16_t*)(W + 75759616);     // over ctx (dead)
    int*    cidx  = (int*)(W + 92536832);        // 32 KB
    int*    nkv   = (int*)(W + 92569600);        // 16 B
    float*  out   = (float*)d_out;

    // fused prep (1/sqrt(S)*log2e folded into Wq)
    prep_all<<<8320, 256, 0, stream>>>(x, xb, Wq, Wk, Wv, WqkvT,
                                       Wo, WoT, W1, W1T, W2, W2T);

    // mask compaction + pad zeroing (before QKV scatter)
    compact_mask<<<4, 256, 0, stream>>>(mask, cidx, nkv, kbuf, vtb);

    // fused QKV projection [8192 x 3072 x 1024]; K/V written compacted
    gemm_bf16<128, 128, 2><<<dim3(24, 64), 256, 0, stream>>>(
        xb, WqkvT, qbuf, kbuf, vtb, bq, bk, bv, cidx, M_, 3072, 1024);

    attn_mfma<<<dim3(1024), 256, 0, stream>>>(qbuf, kbuf, vtb, nkv, ctx);

    // output projection -> bf16 t1
    gemm_bf16<128, 128, 0><<<dim3(8, 64), 256, 0, stream>>>(
        ctx, WoT, t1b, nullptr, nullptr, bo, nullptr, nullptr, nullptr, M_, 1024, 1024);

    ln_kernel<bf16_t, bf16_t><<<8192, 256, 0, stream>>>(t1b, g1, b1, hb);

    // FFN1 (N=64) + exact GELU -> bf16
    gemm_bf16<32, 64, 1><<<dim3(1, 256), 256, 0, stream>>>(
        hb, W1T, f1b, nullptr, nullptr, c1, nullptr, nullptr, nullptr, M_, 64, 1024);

    // FFN2 (K=64) -> bf16
    gemm_bf16<128, 128, 0><<<dim3(8, 64), 256, 0, stream>>>(
        f1b, W2T, f2b, nullptr, nullptr, c2, nullptr, nullptr, nullptr, M_, 1024, 64);

    ln_kernel<bf16_t, float><<<8192, 256, 0, stream>>>(f2b, g2, b2, out);
}

// Round 11
// 224.705 us; speedup vs baseline: 1.0714x; 1.0420x over previous
//
#include <hip/hip_runtime.h>
#include <math.h>

#define B_ 4
#define S_ 2048
#define E_ 1024
#define H_ 16
#define D_ 64
#define M_ (B_*S_)
// 1/sqrt(2048) * log2(e): scale folded into Wq/bq so softmax uses exp2 directly
#define QSCALE (0.022097086912079608f * 1.4426950408889634f)

typedef __bf16 bf16_t;
typedef __bf16 bf16x8 __attribute__((ext_vector_type(8)));
typedef float  f32x4  __attribute__((ext_vector_type(4)));

// async global->LDS, 16B per lane. LDS dest must be linear (base + lane*16).
__device__ __forceinline__ void gload_lds16(const void* g, void* l) {
    __builtin_amdgcn_global_load_lds(
        (const __attribute__((address_space(1))) void*)g,
        (__attribute__((address_space(3))) void*)l, 16, 0, 0);
}
__device__ __forceinline__ bf16x8 ldsx8(const void* p) {
    return __builtin_bit_cast(bf16x8, *(const uint4*)p);
}
__device__ __forceinline__ unsigned short bf16bits(float x) {
    return __builtin_bit_cast(unsigned short, (bf16_t)x);
}
// swizzle for K-tile QK^T A-frag read rows {32c + 8a + 4kf + b}: f = (b + 2a) & 7
__device__ __forceinline__ int fk(int row) { return ((row & 3) + 2 * ((row >> 3) & 3)) & 7; }

// ---------------------------------------------------------------------------
// bf16 MFMA GEMM, C = A[M,K] x Bt[N,K]^T. BK=64, 4 waves, wave tile (BM/2)x(BN/2).
// Grid flattened + bijective XCD swizzle (requires nwg % 8 == 0).
// MODE 0: bf16 out + bias. MODE 1: bf16 out + bias + exact GELU.
// MODE 2: QKV scatter; Q bias scaled by QSCALE; V written transposed as
//         vt[bh][d][s] (raw, uncompacted). All stores contiguous (R8 form).
// ---------------------------------------------------------------------------
template<int BM, int BN, int MODE>
__global__ __launch_bounds__(256) void gemm_bf16(
    const bf16_t* __restrict__ A, const bf16_t* __restrict__ Bt,
    bf16_t* __restrict__ ob0, bf16_t* __restrict__ ob1, bf16_t* __restrict__ ob2,
    const float* __restrict__ bias0, const float* __restrict__ bias1,
    const float* __restrict__ bias2,
    int M, int N, int K)
{
    constexpr int FM = BM / 32, FN = BN / 32;
    __shared__ bf16_t As[BM * 64];
    __shared__ bf16_t Bs[BN * 64];

    const int tid = threadIdx.x;
    const int w   = tid >> 6;
    const int wr  = w >> 1, wc = w & 1;
    const int lr  = tid & 15;
    const int lg  = (tid >> 4) & 3;

    // XCD-bijective block swizzle: 8 contiguous chunks, one per XCD
    const int nwg  = gridDim.x * gridDim.y;
    int bidf = blockIdx.y * gridDim.x + blockIdx.x;
    bidf = (bidf & 7) * (nwg >> 3) + (bidf >> 3);
    const int bm = (bidf / gridDim.x) * BM;
    const int bn = (bidf % gridDim.x) * BN;

    f32x4 acc[FM][FN] = {};

    for (int kk = 0; kk < K; kk += 64) {
        __syncthreads();
        #pragma unroll
        for (int i = 0; i < BM / 32; ++i) {
            int idx = i * 256 + tid;
            int row = idx >> 3, slot = idx & 7;
            gload_lds16(A + (size_t)(bm + row) * K + kk + (slot ^ (row & 7)) * 8,
                        (char*)As + idx * 16);
        }
        #pragma unroll
        for (int i = 0; i < BN / 32; ++i) {
            int idx = i * 256 + tid;
            int row = idx >> 3, slot = idx & 7;
            gload_lds16(Bt + (size_t)(bn + row) * K + kk + (slot ^ (row & 7)) * 8,
                        (char*)Bs + idx * 16);
        }
        __syncthreads();

        #pragma unroll
        for (int h = 0; h < 2; ++h) {
            bf16x8 af[FM], bfr[FN];
            #pragma unroll
            for (int m = 0; m < FM; ++m) {
                int row = wr * (BM / 2) + m * 16 + lr;
                af[m] = ldsx8((char*)As + row * 128 + (((4 * h + lg) ^ (row & 7)) << 4));
            }
            #pragma unroll
            for (int n = 0; n < FN; ++n) {
                int col = wc * (BN / 2) + n * 16 + lr;
                bfr[n] = ldsx8((char*)Bs + col * 128 + (((4 * h + lg) ^ (col & 7)) << 4));
            }
            #pragma unroll
            for (int m = 0; m < FM; ++m)
                #pragma unroll
                for (int n = 0; n < FN; ++n)
                    acc[m][n] = __builtin_amdgcn_mfma_f32_16x16x32_bf16(
                        af[m], bfr[n], acc[m][n], 0, 0, 0);
        }
    }

    #pragma unroll
    for (int n = 0; n < FN; ++n) {
        const int gcol = bn + wc * (BN / 2) + n * 16 + lr;
        if constexpr (MODE == 2) {
            const int p = gcol >> 10, nn = gcol & 1023;
            const float bv = (p == 0) ? bias0[nn] * QSCALE
                           : (p == 1) ? bias1[nn] : bias2[nn];
            #pragma unroll
            for (int m = 0; m < FM; ++m) {
                const int grow0 = bm + wr * (BM / 2) + m * 16 + lg * 4;
                if (p == 2) {   // V: write transposed [bh][d][s], 4 s contiguous
                    ushort4 o;
                    o.x = bf16bits(acc[m][n][0] + bv);
                    o.y = bf16bits(acc[m][n][1] + bv);
                    o.z = bf16bits(acc[m][n][2] + bv);
                    o.w = bf16bits(acc[m][n][3] + bv);
                    const int bb = grow0 >> 11, s = grow0 & 2047;
                    *(ushort4*)(ob2 + (((size_t)(bb << 10) + nn) << 11) + s) = o;
                } else {
                    bf16_t* o = (p == 0) ? ob0 : ob1;
                    #pragma unroll
                    for (int r = 0; r < 4; ++r)
                        o[((size_t)(grow0 + r) << 10) + nn] = (bf16_t)(acc[m][n][r] + bv);
                }
            }
        } else {
            const float bv = bias0[gcol];
            #pragma unroll
            for (int m = 0; m < FM; ++m)
                #pragma unroll
                for (int r = 0; r < 4; ++r) {
                    const int grow = bm + wr * (BM / 2) + m * 16 + lg * 4 + r;
                    float v = acc[m][n][r] + bv;
                    if constexpr (MODE == 1)
                        v = 0.5f * v * (1.0f + erff(v * 0.70710678118654752f));
                    ob0[(size_t)grow * N + gcol] = (bf16_t)v;
                }
        }
    }
}

// ---------------------------------------------------------------------------
// Mask compaction: order-preserving scan -> sidx[b][ci] = original s
// (pad ci in [nk, nkp) -> 0), nkv[b] = survivor count. Also zeroes pad
// columns [nk, nkp) of compact V^T. grid 4, 256 threads.
// ---------------------------------------------------------------------------
__global__ __launch_bounds__(256) void compact_mask(
    const int* __restrict__ mask, int* __restrict__ sidx,
    int* __restrict__ nkv, bf16_t* __restrict__ vtc)
{
    __shared__ int wsum[4];
    const int b = blockIdx.x;
    const int tid = threadIdx.x;
    const int lane = tid & 63, wv = tid >> 6;
    const int base = tid * 8;

    int m[8], loc[8];
    int cnt = 0;
    #pragma unroll
    for (int j = 0; j < 8; ++j) {
        m[j] = mask[b * S_ + base + j];
        loc[j] = cnt;
        cnt += (m[j] != 0);
    }
    int incl = cnt;
    #pragma unroll
    for (int off = 1; off < 64; off <<= 1) {
        int t = __shfl_up(incl, off);
        if (lane >= off) incl += t;
    }
    if (lane == 63) wsum[wv] = incl;
    const int excl_lane = incl - cnt;
    __syncthreads();
    int wbase = 0;
    for (int i = 0; i < wv; ++i) wbase += wsum[i];
    const int total = wsum[0] + wsum[1] + wsum[2] + wsum[3];
    if (tid == 0) nkv[b] = total;
    const int tbase = wbase + excl_lane;
    #pragma unroll
    for (int j = 0; j < 8; ++j)
        if (m[j]) sidx[b * S_ + tbase + loc[j]] = base + j;

    const int nk = total, nkp = (total + 63) & ~63;
    // pad sidx -> 0 (safe gather target; tail bias kills contribution)
    for (int c = nk + tid; c < nkp; c += 256)
        sidx[b * S_ + c] = 0;
    // zero pad columns of compact V^T for this b (rows b*1024 .. +1023)
    for (int rr = tid; rr < 1024; rr += 256) {
        bf16_t* dst = vtc + (((size_t)(b << 10) + rr) << 11);
        for (int c = nk; c < nkp; ++c) dst[c] = (bf16_t)0.0f;
    }
}

// ---------------------------------------------------------------------------
// V^T compaction gather: vtc[row][c] = vtbr[row][sidx[b][c]], c < nk.
// grid 1024 blocks x 256 thr; each block 4 rows. Writes coalesced.
// ---------------------------------------------------------------------------
__global__ __launch_bounds__(256) void v_gather(
    const bf16_t* __restrict__ vtbr, bf16_t* __restrict__ vtc,
    const int* __restrict__ sidx, const int* __restrict__ nkv)
{
    const int tid = threadIdx.x;
    const int row4 = blockIdx.x;          // [0,1024): rows row4*4 .. +3
    const int b = row4 >> 8;              // 256 row-quads per batch
    const int nk = nkv[b];
    const int* sb = sidx + b * S_;
    #pragma unroll
    for (int rr = 0; rr < 4; ++rr) {
        const size_t row = (size_t)row4 * 4 + rr;
        const bf16_t* src = vtbr + (row << 11);
        bf16_t* dst = vtc + (row << 11);
        for (int c = tid; c < nk; c += 256)
            dst[c] = src[sb[c]];
    }
}

// ---------------------------------------------------------------------------
// MFMA flash attention over COMPACTED keys. K gathered on the fly via sidx
// (global_load_lds source is per-lane); V^T physically compacted (vtc).
// Zero-shuffle P path, 4 waves x 32 q-rows, KVBLK=64, dbuf stage-early.
// Full tiles: z init = 0 (no mask op). Tail tile: 4-compare register bias.
// L via ones-row MFMA; exp2-domain scores. 8 bh per XCD.
// ---------------------------------------------------------------------------
__global__ __launch_bounds__(256) void attn_mfma(
    const bf16_t* __restrict__ qg, const bf16_t* __restrict__ kg,
    const bf16_t* __restrict__ vg, const int* __restrict__ sidx,
    const int* __restrict__ nkv, bf16_t* __restrict__ ctx)
{
    __shared__ bf16_t ks[2][64 * 64];   // [key][d] 128B rows, fk-swizzled
    __shared__ bf16_t vts[2][64 * 64];  // [d][key] 128B rows, row&7-swizzled

    const int tid = threadIdx.x;
    const int w   = tid >> 6;
    const int lr  = tid & 15;
    const int lg  = (tid >> 4) & 3;

    const int bid = blockIdx.x;
    const int xcd = bid & 7, kidx = bid >> 3;        // kidx in [0,128)
    const int bh  = xcd * 8 + (kidx >> 4);           // 8 bh per XCD
    const int xq  = kidx & 15;                       // 16 q-blocks of 128
    const int b   = bh >> 4, h = bh & 15;
    const int q0w = xq * 128 + w * 32;               // wave owns 32 q-rows

    const int nk = nkv[b];
    const int ntiles = (nk + 63) >> 6;
    const bool hastail = (nk & 63) != 0;
    const int* sb = sidx + b * S_;

    bf16x8 aq[2][2];
    #pragma unroll
    for (int f = 0; f < 2; ++f) {
        const bf16_t* qp = qg + ((size_t)(b * S_ + q0w + f * 16 + lr) << 10) + h * 64 + lg * 8;
        aq[f][0] = ldsx8(qp);
        aq[f][1] = ldsx8(qp + 32);
    }

    bf16x8 onesf;
    {
        bf16_t o1 = (bf16_t)((lr == 0) ? 1.0f : 0.0f);
        #pragma unroll
        for (int j = 0; j < 8; ++j) onesf[j] = o1;
    }

    int koff[2][2][2], voff[2][4];
    #pragma unroll
    for (int c = 0; c < 2; ++c) {
        #pragma unroll
        for (int kf1 = 0; kf1 < 2; ++kf1) {
            const int row = c * 32 + 8 * (lr >> 2) + 4 * kf1 + (lr & 3);
            const int f = fk(row);
            koff[c][kf1][0] = row * 128 + ((lg ^ f) << 4);
            koff[c][kf1][1] = row * 128 + (((4 + lg) ^ f) << 4);
        }
        #pragma unroll
        for (int n = 0; n < 4; ++n) {
            const int rowv = n * 16 + lr;
            voff[c][n] = rowv * 128 + (((4 * c + lg) ^ (rowv & 7)) << 4);
        }
    }

    // staging: K via per-tile sidx gather; V incremental along compact s
    const int srow = tid >> 3, sslot = tid & 7;     // srow in [0,32)
    const bf16_t* vptr[2];
    char* kdst[2];
    char* vdst[2];
    int ksw[2];
    #pragma unroll
    for (int it = 0; it < 2; ++it) {
        const int idx = it * 256 + tid;
        const int row = idx >> 3;                    // it*32 + srow
        vptr[it] = vg + (((size_t)bh * 64 + row) << 11) + ((sslot ^ (row & 7)) << 3);
        kdst[it] = (char*)ks + idx * 16;
        vdst[it] = (char*)vts + idx * 16;
        ksw[it]  = h * 64 + ((sslot ^ fk(row)) << 3);
    }

    f32x4 accO[2][4] = {};
    f32x4 accL[2] = {};

    auto STAGE = [&](int buf, int t0) {
        const int nb = buf << 13;
        #pragma unroll
        for (int it = 0; it < 2; ++it) {
            const int sv = sb[t0 + it * 32 + srow];
            gload_lds16(kg + ((size_t)(b * S_ + sv) << 10) + ksw[it], kdst[it] + nb);
            gload_lds16(vptr[it], vdst[it] + nb);
            vptr[it] += 64;
        }
    };

    auto COMPUTE = [&](int buf, int t0, bool tl) {
        const char* ksb = (const char*)ks + (buf << 13);
        const char* vsb = (const char*)vts + (buf << 13);
        #pragma unroll
        for (int c = 0; c < 2; ++c) {
            unsigned int pw0[4], pw1[4];
            #pragma unroll
            for (int kf1 = 0; kf1 < 2; ++kf1) {
                bf16x8 a0 = ldsx8(ksb + koff[c][kf1][0]);
                bf16x8 a1 = ldsx8(ksb + koff[c][kf1][1]);
                f32x4 z0 = {}, z1 = {};
                if (tl) {
                    const int keyb = t0 + c * 32 + 8 * lg + 4 * kf1;
                    f32x4 bias;
                    #pragma unroll
                    for (int r = 0; r < 4; ++r)
                        bias[r] = (keyb + r < nk) ? 0.0f : -1.0e9f;
                    z0 = bias; z1 = bias;
                }
                __builtin_amdgcn_s_setprio(1);
                z0 = __builtin_amdgcn_mfma_f32_16x16x32_bf16(a0, aq[0][0], z0, 0, 0, 0);
                z0 = __builtin_amdgcn_mfma_f32_16x16x32_bf16(a1, aq[0][1], z0, 0, 0, 0);
                z1 = __builtin_amdgcn_mfma_f32_16x16x32_bf16(a0, aq[1][0], z1, 0, 0, 0);
                z1 = __builtin_amdgcn_mfma_f32_16x16x32_bf16(a1, aq[1][1], z1, 0, 0, 0);
                __builtin_amdgcn_s_setprio(0);
                const float p00 = __builtin_amdgcn_exp2f(z0[0]);
                const float p01 = __builtin_amdgcn_exp2f(z0[1]);
                const float p02 = __builtin_amdgcn_exp2f(z0[2]);
                const float p03 = __builtin_amdgcn_exp2f(z0[3]);
                const float p10 = __builtin_amdgcn_exp2f(z1[0]);
                const float p11 = __builtin_amdgcn_exp2f(z1[1]);
                const float p12 = __builtin_amdgcn_exp2f(z1[2]);
                const float p13 = __builtin_amdgcn_exp2f(z1[3]);
                pw0[2 * kf1]     = bf16bits(p00) | ((unsigned)bf16bits(p01) << 16);
                pw0[2 * kf1 + 1] = bf16bits(p02) | ((unsigned)bf16bits(p03) << 16);
                pw1[2 * kf1]     = bf16bits(p10) | ((unsigned)bf16bits(p11) << 16);
                pw1[2 * kf1 + 1] = bf16bits(p12) | ((unsigned)bf16bits(p13) << 16);
            }
            uint4 pk0 = {pw0[0], pw0[1], pw0[2], pw0[3]};
            uint4 pk1 = {pw1[0], pw1[1], pw1[2], pw1[3]};
            const bf16x8 pa0 = __builtin_bit_cast(bf16x8, pk0);
            const bf16x8 pa1 = __builtin_bit_cast(bf16x8, pk1);

            __builtin_amdgcn_s_setprio(1);
            #pragma unroll
            for (int n = 0; n < 4; ++n) {
                bf16x8 av = ldsx8(vsb + voff[c][n]);
                accO[0][n] = __builtin_amdgcn_mfma_f32_16x16x32_bf16(av, pa0, accO[0][n], 0, 0, 0);
                accO[1][n] = __builtin_amdgcn_mfma_f32_16x16x32_bf16(av, pa1, accO[1][n], 0, 0, 0);
            }
            accL[0] = __builtin_amdgcn_mfma_f32_16x16x32_bf16(onesf, pa0, accL[0], 0, 0, 0);
            accL[1] = __builtin_amdgcn_mfma_f32_16x16x32_bf16(onesf, pa1, accL[1], 0, 0, 0);
            __builtin_amdgcn_s_setprio(0);
        }
    };

    STAGE(0, 0);
    __syncthreads();

    int cur = 0;
    for (int t = 0; t < ntiles; ++t) {
        if (t + 1 < ntiles) STAGE(cur ^ 1, (t + 1) * 64);
        COMPUTE(cur, t * 64, hastail && (t == ntiles - 1));
        __syncthreads();
        cur ^= 1;
    }

    #pragma unroll
    for (int f = 0; f < 2; ++f) {
        const float inv = 1.0f / __shfl(accL[f][0], lr);
        bf16_t* obase = ctx + ((size_t)(b * S_ + q0w + f * 16 + lr) << 10) + h * 64;
        #pragma unroll
        for (int n = 0; n < 4; ++n) {
            ushort4 o;
            o.x = bf16bits(accO[f][n][0] * inv);
            o.y = bf16bits(accO[f][n][1] * inv);
            o.z = bf16bits(accO[f][n][2] * inv);
            o.w = bf16bits(accO[f][n][3] * inv);
            *(ushort4*)(obase + n * 16 + lg * 4) = o;
        }
    }
}

// ---------------------------------------------------------------------------
// Fused prep: x cast + all 5 weight transpose/converts, one launch.
// ---------------------------------------------------------------------------
__global__ __launch_bounds__(256) void prep_all(
    const float* __restrict__ x, bf16_t* __restrict__ xb,
    const float* __restrict__ Wq, const float* __restrict__ Wk,
    const float* __restrict__ Wv, bf16_t* __restrict__ WqkvT,
    const float* __restrict__ Wo, bf16_t* __restrict__ WoT,
    const float* __restrict__ W1, bf16_t* __restrict__ W1T,
    const float* __restrict__ W2, bf16_t* __restrict__ W2T)
{
    __shared__ float t[32][33];
    const int tid = threadIdx.x;
    int bid = blockIdx.x;

    if (bid < 4096) {               // x f32 -> bf16, 8 per thread
        int i = bid * 256 + tid;
        float4 a = ((const float4*)x)[i * 2];
        float4 b = ((const float4*)x)[i * 2 + 1];
        unsigned int p0 = bf16bits(a.x) | ((unsigned)bf16bits(a.y) << 16);
        unsigned int p1 = bf16bits(a.z) | ((unsigned)bf16bits(a.w) << 16);
        unsigned int p2 = bf16bits(b.x) | ((unsigned)bf16bits(b.y) << 16);
        unsigned int p3 = bf16bits(b.z) | ((unsigned)bf16bits(b.w) << 16);
        uint4 o = {p0, p1, p2, p3};
        ((uint4*)xb)[i] = o;
        return;
    }
    bid -= 4096;

    const float* in; bf16_t* out;
    int R, C, c0, r0;
    float scale = 1.0f;
    if (bid < 3072) {               // Wq/Wk/Wv [16][1024][64] -> per-head [64][1024]
        const int p = bid >> 10, r = bid & 1023;
        const int z = r >> 6, rem = r & 63;
        in  = (p == 0 ? Wq : p == 1 ? Wk : Wv) + z * 65536;
        out = WqkvT + p * 1048576 + z * 65536;
        R = 1024; C = 64;
        c0 = (rem & 1) * 32; r0 = (rem >> 1) * 32;
        if (p == 0) scale = QSCALE;
    } else if (bid < 4096) {        // Wo [1024][1024]
        const int r = bid - 3072;
        in = Wo; out = WoT; R = 1024; C = 1024;
        c0 = (r & 31) * 32; r0 = (r >> 5) * 32;
    } else if (bid < 4160) {        // W1 [1024][64]
        const int r = bid - 4096;
        in = W1; out = W1T; R = 1024; C = 64;
        c0 = (r & 1) * 32; r0 = (r >> 1) * 32;
    } else {                        // W2 [64][1024]
        const int r = bid - 4160;
        in = W2; out = W2T; R = 64; C = 1024;
        c0 = (r & 31) * 32; r0 = (r >> 5) * 32;
    }

    {
        int rr = tid >> 3, c4 = (tid & 7) * 4;
        float4 v = *(const float4*)&in[(size_t)(r0 + rr) * C + c0 + c4];
        t[rr][c4 + 0] = v.x * scale;
        t[rr][c4 + 1] = v.y * scale;
        t[rr][c4 + 2] = v.z * scale;
        t[rr][c4 + 3] = v.w * scale;
    }
    __syncthreads();
    {
        int c = tid >> 3, r4 = (tid & 7) * 4;
        ushort4 o;
        o.x = bf16bits(t[r4 + 0][c]);
        o.y = bf16bits(t[r4 + 1][c]);
        o.z = bf16bits(t[r4 + 2][c]);
        o.w = bf16bits(t[r4 + 3][c]);
        *(ushort4*)(out + (size_t)(c0 + c) * R + r0 + r4) = o;
    }
}

// ---------------------------------------------------------------------------
// Row LayerNorm over 1024. InT: float or bf16; OutT: float or bf16.
// ---------------------------------------------------------------------------
template<typename InT, typename OutT>
__global__ __launch_bounds__(256) void ln_kernel(
    const InT* __restrict__ in, const float* __restrict__ g,
    const float* __restrict__ bta, OutT* __restrict__ out)
{
    const int row = blockIdx.x;
    const int tid = threadIdx.x;

    float x0, x1, x2, x3;
    if constexpr (sizeof(InT) == 4) {
        float4 xv = ((const float4*)(in + (size_t)row * E_))[tid];
        x0 = xv.x; x1 = xv.y; x2 = xv.z; x3 = xv.w;
    } else {
        ushort4 xv = *(const ushort4*)((const bf16_t*)in + (size_t)row * E_ + tid * 4);
        x0 = (float)__builtin_bit_cast(bf16_t, xv.x);
        x1 = (float)__builtin_bit_cast(bf16_t, xv.y);
        x2 = (float)__builtin_bit_cast(bf16_t, xv.z);
        x3 = (float)__builtin_bit_cast(bf16_t, xv.w);
    }
    float s  = x0 + x1 + x2 + x3;
    float sq = x0 * x0 + x1 * x1 + x2 * x2 + x3 * x3;
    #pragma unroll
    for (int off = 32; off > 0; off >>= 1) {
        s  += __shfl_down(s, off);
        sq += __shfl_down(sq, off);
    }
    __shared__ float ss[4], ssq[4];
    if ((tid & 63) == 0) { ss[tid >> 6] = s; ssq[tid >> 6] = sq; }
    __syncthreads();
    s  = ss[0] + ss[1] + ss[2] + ss[3];
    sq = ssq[0] + ssq[1] + ssq[2] + ssq[3];

    const float mean = s * (1.0f / E_);
    const float var  = sq * (1.0f / E_) - mean * mean;
    const float rstd = rsqrtf(var + 1e-5f);

    float4 gv = ((const float4*)g)[tid];
    float4 bv = ((const float4*)bta)[tid];
    float o0 = (x0 - mean) * rstd * gv.x + bv.x;
    float o1 = (x1 - mean) * rstd * gv.y + bv.y;
    float o2 = (x2 - mean) * rstd * gv.z + bv.z;
    float o3 = (x3 - mean) * rstd * gv.w + bv.w;
    if constexpr (sizeof(OutT) == 4) {
        float4 o = {o0, o1, o2, o3};
        ((float4*)((float*)out + (size_t)row * E_))[tid] = o;
    } else {
        ushort4 o;
        o.x = bf16bits(o0); o.y = bf16bits(o1);
        o.z = bf16bits(o2); o.w = bf16bits(o3);
        *(ushort4*)((bf16_t*)out + (size_t)row * E_ + tid * 4) = o;
    }
}

// ---------------------------------------------------------------------------
extern "C" void kernel_launch(void* const* d_in, const int* in_sizes, int n_in,
                              void* d_out, int out_size, void* d_ws, size_t ws_size,
                              hipStream_t stream)
{
    const float* x    = (const float*)d_in[0];
    const int*   mask = (const int*)d_in[1];
    const float* Wq   = (const float*)d_in[2];
    const float* bq   = (const float*)d_in[3];
    const float* Wk   = (const float*)d_in[4];
    const float* bk   = (const float*)d_in[5];
    const float* Wv   = (const float*)d_in[6];
    const float* bv   = (const float*)d_in[7];
    const float* Wo   = (const float*)d_in[8];
    const float* bo   = (const float*)d_in[9];
    const float* g1   = (const float*)d_in[10];
    const float* b1   = (const float*)d_in[11];
    const float* W1   = (const float*)d_in[12];
    const float* c1   = (const float*)d_in[13];
    const float* W2   = (const float*)d_in[14];
    const float* c2   = (const float*)d_in[15];
    const float* g2   = (const float*)d_in[16];
    const float* b2   = (const float*)d_in[17];

    char* W = (char*)d_ws;                       // peak ~109.4 MB
    bf16_t* xb    = (bf16_t*)(W + 0);            // 16 MB
    bf16_t* WqkvT = (bf16_t*)(W + 16777216);     //  6 MB [3][1024 n][1024 k]
    bf16_t* WoT   = (bf16_t*)(W + 23068672);     //  2 MB
    bf16_t* W1T   = (bf16_t*)(W + 25165824);     //  128K
    bf16_t* W2T   = (bf16_t*)(W + 25296896);     //  128K
    bf16_t* qbuf  = (bf16_t*)(W + 25427968);     // 16 MB [b,s,h,d]
    bf16_t* kbuf  = (bf16_t*)(W + 42205184);     // 16 MB [b,s,h,d] raw
    bf16_t* vtbr  = (bf16_t*)(W + 58982400);     // 16 MB [bh][d][s] raw
    bf16_t* vtc   = (bf16_t*)(W + 75759616);     // 16 MB [bh][d][s_c] compact
    bf16_t* ctx   = (bf16_t*)(W + 92536832);     // 16 MB
    bf16_t* t1b   = (bf16_t*)(W + 25427968);     // over qbuf (dead after attn)
    bf16_t* hb    = (bf16_t*)(W + 42205184);     // over kbuf (dead after attn)
    bf16_t* f1b   = (bf16_t*)(W + 0);            // over xb (dead after QKV)
    bf16_t* f2b   = (bf16_t*)(W + 58982400);     // over vtbr (dead after gather)
    int*    sidx  = (int*)(W + 109314048);       // 32 KB
    int*    nkv   = (int*)(W + 109346816);       // 16 B
    float*  out   = (float*)d_out;

    // fused prep (1/sqrt(S)*log2e folded into Wq)
    prep_all<<<8320, 256, 0, stream>>>(x, xb, Wq, Wk, Wv, WqkvT,
                                       Wo, WoT, W1, W1T, W2, W2T);

    // mask scan -> sidx / nkv; zero compact-V^T pad columns
    compact_mask<<<4, 256, 0, stream>>>(mask, sidx, nkv, vtc);

    // fused QKV projection [8192 x 3072 x 1024]; all stores contiguous
    gemm_bf16<128, 128, 2><<<dim3(24, 64), 256, 0, stream>>>(
        xb, WqkvT, qbuf, kbuf, vtbr, bq, bk, bv, M_, 3072, 1024);

    // V^T compaction (coalesced writes)
    v_gather<<<1024, 256, 0, stream>>>(vtbr, vtc, sidx, nkv);

    // attention over compacted keys (K gathered in-stage via sidx)
    attn_mfma<<<dim3(1024), 256, 0, stream>>>(qbuf, kbuf, vtc, sidx, nkv, ctx);

    // output projection -> bf16 t1
    gemm_bf16<128, 128, 0><<<dim3(8, 64), 256, 0, stream>>>(
        ctx, WoT, t1b, nullptr, nullptr, bo, nullptr, nullptr, M_, 1024, 1024);

    ln_kernel<bf16_t, bf16_t><<<8192, 256, 0, stream>>>(t1b, g1, b1, hb);

    // FFN1 (N=64) + exact GELU -> bf16
    gemm_bf16<32, 64, 1><<<dim3(1, 256), 256, 0, stream>>>(
        hb, W1T, f1b, nullptr, nullptr, c1, nullptr, nullptr, M_, 64, 1024);

    // FFN2 (K=64) -> bf16
    gemm_bf16<128, 128, 0><<<dim3(8, 64), 256, 0, stream>>>(
        f1b, W2T, f2b, nullptr, nullptr, c2, nullptr, nullptr, M_, 1024, 64);

    ln_kernel<bf16_t, float><<<8192, 256, 0, stream>>>(f2b, g2, b2, out);
}

// Round 12
// 210.598 us; speedup vs baseline: 1.1431x; 1.0670x over previous
//
#include <hip/hip_runtime.h>
#include <math.h>

#define B_ 4
#define S_ 2048
#define E_ 1024
#define H_ 16
#define D_ 64
#define M_ (B_*S_)
// 1/sqrt(2048) * log2(e): scale folded into Wq/bq so softmax uses exp2 directly
#define QSCALE (0.022097086912079608f * 1.4426950408889634f)

typedef __bf16 bf16_t;
typedef __bf16 bf16x8 __attribute__((ext_vector_type(8)));
typedef float  f32x4  __attribute__((ext_vector_type(4)));

// async global->LDS, 16B per lane. LDS dest must be linear (base + lane*16).
__device__ __forceinline__ void gload_lds16(const void* g, void* l) {
    __builtin_amdgcn_global_load_lds(
        (const __attribute__((address_space(1))) void*)g,
        (__attribute__((address_space(3))) void*)l, 16, 0, 0);
}
__device__ __forceinline__ bf16x8 ldsx8(const void* p) {
    return __builtin_bit_cast(bf16x8, *(const uint4*)p);
}
__device__ __forceinline__ unsigned short bf16bits(float x) {
    return __builtin_bit_cast(unsigned short, (bf16_t)x);
}
// swizzle for K-tile QK^T A-frag read rows {32c + 8a + 4kf + b}: f = (b + 2a) & 7
__device__ __forceinline__ int fk(int row) { return ((row & 3) + 2 * ((row >> 3) & 3)) & 7; }

// ---------------------------------------------------------------------------
// bf16 MFMA GEMM, C = A[M,K] x Bt[N,K]^T. BK=64, 4 waves, wave tile (BM/2)x(BN/2).
// Grid flattened + bijective XCD swizzle (requires nwg % 8 == 0).
// MODE 0: bf16 out + bias (f32 bias, used raw).
// MODE 1: bf16 out + bias + exact GELU.
// MODE 2: compacted KV projection. A-rows gathered via sidx (per-batch compact
//         order); blocks beyond this batch's padded row count exit early.
//         N=2048: cols 0-1023 = K (+bias0) -> ob1[b][ci][nn] contiguous;
//         cols 1024-2047 = V (+bias1) -> ob2[bh][d][ci] (4 consecutive ci).
// ---------------------------------------------------------------------------
template<int BM, int BN, int MODE>
__global__ __launch_bounds__(256) void gemm_bf16(
    const bf16_t* __restrict__ A, const bf16_t* __restrict__ Bt,
    bf16_t* __restrict__ ob0, bf16_t* __restrict__ ob1, bf16_t* __restrict__ ob2,
    const float* __restrict__ bias0, const float* __restrict__ bias1,
    const int* __restrict__ sidx, const int* __restrict__ nkv,
    int M, int N, int K)
{
    constexpr int FM = BM / 32, FN = BN / 32;
    __shared__ bf16_t As[BM * 64];
    __shared__ bf16_t Bs[BN * 64];

    const int tid = threadIdx.x;
    const int w   = tid >> 6;
    const int wr  = w >> 1, wc = w & 1;
    const int lr  = tid & 15;
    const int lg  = (tid >> 4) & 3;

    // XCD-bijective block swizzle: 8 contiguous chunks, one per XCD
    const int nwg  = gridDim.x * gridDim.y;
    int bidf = blockIdx.y * gridDim.x + blockIdx.x;
    bidf = (bidf & 7) * (nwg >> 3) + (bidf >> 3);
    const int bm = (bidf / gridDim.x) * BM;
    const int bn = (bidf % gridDim.x) * BN;

    // MODE 2: early-exit past this batch's compact rows; hoist gathered rows
    int arow[FM];
    if constexpr (MODE == 2) {
        const int b2 = bm >> 11, rbase = bm & 2047;
        const int nkp128 = (nkv[b2] + 127) & ~127;
        if (rbase >= nkp128) return;
        #pragma unroll
        for (int i = 0; i < FM; ++i) {
            const int row = (i * 256 + tid) >> 3;
            arow[i] = (b2 << 11) + sidx[(b2 << 11) + rbase + row];
        }
    }

    f32x4 acc[FM][FN] = {};

    for (int kk = 0; kk < K; kk += 64) {
        __syncthreads();
        #pragma unroll
        for (int i = 0; i < BM / 32; ++i) {
            int idx = i * 256 + tid;
            int row = idx >> 3, slot = idx & 7;
            const size_t grow = (MODE == 2) ? (size_t)arow[i] : (size_t)(bm + row);
            gload_lds16(A + grow * K + kk + (slot ^ (row & 7)) * 8,
                        (char*)As + idx * 16);
        }
        #pragma unroll
        for (int i = 0; i < BN / 32; ++i) {
            int idx = i * 256 + tid;
            int row = idx >> 3, slot = idx & 7;
            gload_lds16(Bt + (size_t)(bn + row) * K + kk + (slot ^ (row & 7)) * 8,
                        (char*)Bs + idx * 16);
        }
        __syncthreads();

        #pragma unroll
        for (int h = 0; h < 2; ++h) {
            bf16x8 af[FM], bfr[FN];
            #pragma unroll
            for (int m = 0; m < FM; ++m) {
                int row = wr * (BM / 2) + m * 16 + lr;
                af[m] = ldsx8((char*)As + row * 128 + (((4 * h + lg) ^ (row & 7)) << 4));
            }
            #pragma unroll
            for (int n = 0; n < FN; ++n) {
                int col = wc * (BN / 2) + n * 16 + lr;
                bfr[n] = ldsx8((char*)Bs + col * 128 + (((4 * h + lg) ^ (col & 7)) << 4));
            }
            #pragma unroll
            for (int m = 0; m < FM; ++m)
                #pragma unroll
                for (int n = 0; n < FN; ++n)
                    acc[m][n] = __builtin_amdgcn_mfma_f32_16x16x32_bf16(
                        af[m], bfr[n], acc[m][n], 0, 0, 0);
        }
    }

    #pragma unroll
    for (int n = 0; n < FN; ++n) {
        const int gcol = bn + wc * (BN / 2) + n * 16 + lr;
        if constexpr (MODE == 2) {
            const int p = gcol >> 10, nn = gcol & 1023;
            const int b2 = bm >> 11;
            const float bvl = p ? bias1[nn] : bias0[nn];
            #pragma unroll
            for (int m = 0; m < FM; ++m) {
                const int ci0 = (bm & 2047) + wr * (BM / 2) + m * 16 + lg * 4;
                if (p) {    // V^T: vtc[((b*1024 + nn) << 11) + ci], 4 consecutive ci
                    ushort4 o;
                    o.x = bf16bits(acc[m][n][0] + bvl);
                    o.y = bf16bits(acc[m][n][1] + bvl);
                    o.z = bf16bits(acc[m][n][2] + bvl);
                    o.w = bf16bits(acc[m][n][3] + bvl);
                    *(ushort4*)(ob2 + ((((size_t)b2 << 10) + nn) << 11) + ci0) = o;
                } else {    // K: kbuf[((b<<11) + ci) << 10 + nn]
                    #pragma unroll
                    for (int r = 0; r < 4; ++r)
                        ob1[((size_t)((b2 << 11) + ci0 + r) << 10) + nn] =
                            (bf16_t)(acc[m][n][r] + bvl);
                }
            }
        } else {
            const float bvl = bias0[gcol];
            #pragma unroll
            for (int m = 0; m < FM; ++m)
                #pragma unroll
                for (int r = 0; r < 4; ++r) {
                    const int grow = bm + wr * (BM / 2) + m * 16 + lg * 4 + r;
                    float v = acc[m][n][r] + bvl;
                    if constexpr (MODE == 1)
                        v = 0.5f * v * (1.0f + erff(v * 0.70710678118654752f));
                    ob0[(size_t)grow * N + gcol] = (bf16_t)v;
                }
        }
    }
}

// ---------------------------------------------------------------------------
// Mask compaction: order-preserving scan -> sidx[b][ci] = original s,
// padded with 0 up to the next multiple of 128 (KV-GEMM block granularity).
// nkv[b] = survivor count. grid 4, 256 threads.
// ---------------------------------------------------------------------------
__global__ __launch_bounds__(256) void compact_mask(
    const int* __restrict__ mask, int* __restrict__ sidx, int* __restrict__ nkv)
{
    __shared__ int wsum[4];
    const int b = blockIdx.x;
    const int tid = threadIdx.x;
    const int lane = tid & 63, wv = tid >> 6;
    const int base = tid * 8;

    int m[8], loc[8];
    int cnt = 0;
    #pragma unroll
    for (int j = 0; j < 8; ++j) {
        m[j] = mask[b * S_ + base + j];
        loc[j] = cnt;
        cnt += (m[j] != 0);
    }
    int incl = cnt;
    #pragma unroll
    for (int off = 1; off < 64; off <<= 1) {
        int t = __shfl_up(incl, off);
        if (lane >= off) incl += t;
    }
    if (lane == 63) wsum[wv] = incl;
    const int excl_lane = incl - cnt;
    __syncthreads();
    int wbase = 0;
    for (int i = 0; i < wv; ++i) wbase += wsum[i];
    const int total = wsum[0] + wsum[1] + wsum[2] + wsum[3];
    if (tid == 0) nkv[b] = total;
    const int tbase = wbase + excl_lane;
    #pragma unroll
    for (int j = 0; j < 8; ++j)
        if (m[j]) sidx[b * S_ + tbase + loc[j]] = base + j;

    // pad sidx -> 0 (safe gather target) up to 128-multiple
    const int nkp = (total + 127) & ~127;
    for (int c = total + tid; c < nkp; c += 256)
        sidx[b * S_ + c] = 0;
}

// ---------------------------------------------------------------------------
// MFMA flash attention over COMPACTED keys (K and V^T physically compact).
// Zero-shuffle P path, 4 waves x 32 q-rows, KVBLK=64, dbuf stage-early.
// Full tiles: z init = 0 (no mask op). Tail tile: 4-compare register bias
// (pad slots hold finite row-0 projections; bias -1e9 -> p = 0 exactly).
// L via ones-row MFMA; exp2-domain scores. 8 bh per XCD.
// ---------------------------------------------------------------------------
__global__ __launch_bounds__(256) void attn_mfma(
    const bf16_t* __restrict__ qg, const bf16_t* __restrict__ kg,
    const bf16_t* __restrict__ vg, const int* __restrict__ nkv,
    bf16_t* __restrict__ ctx)
{
    __shared__ bf16_t ks[2][64 * 64];   // [key][d] 128B rows, fk-swizzled
    __shared__ bf16_t vts[2][64 * 64];  // [d][key] 128B rows, row&7-swizzled

    const int tid = threadIdx.x;
    const int w   = tid >> 6;
    const int lr  = tid & 15;
    const int lg  = (tid >> 4) & 3;

    const int bid = blockIdx.x;
    const int xcd = bid & 7, kidx = bid >> 3;        // kidx in [0,128)
    const int bh  = xcd * 8 + (kidx >> 4);           // 8 bh per XCD
    const int xq  = kidx & 15;                       // 16 q-blocks of 128
    const int b   = bh >> 4, h = bh & 15;
    const int q0w = xq * 128 + w * 32;               // wave owns 32 q-rows

    const int nk = nkv[b];
    const int ntiles = (nk + 63) >> 6;
    const bool hastail = (nk & 63) != 0;

    bf16x8 aq[2][2];
    #pragma unroll
    for (int f = 0; f < 2; ++f) {
        const bf16_t* qp = qg + ((size_t)(b * S_ + q0w + f * 16 + lr) << 10) + h * 64 + lg * 8;
        aq[f][0] = ldsx8(qp);
        aq[f][1] = ldsx8(qp + 32);
    }

    bf16x8 onesf;
    {
        bf16_t o1 = (bf16_t)((lr == 0) ? 1.0f : 0.0f);
        #pragma unroll
        for (int j = 0; j < 8; ++j) onesf[j] = o1;
    }

    int koff[2][2][2], voff[2][4];
    #pragma unroll
    for (int c = 0; c < 2; ++c) {
        #pragma unroll
        for (int kf1 = 0; kf1 < 2; ++kf1) {
            const int row = c * 32 + 8 * (lr >> 2) + 4 * kf1 + (lr & 3);
            const int f = fk(row);
            koff[c][kf1][0] = row * 128 + ((lg ^ f) << 4);
            koff[c][kf1][1] = row * 128 + (((4 + lg) ^ f) << 4);
        }
        #pragma unroll
        for (int n = 0; n < 4; ++n) {
            const int rowv = n * 16 + lr;
            voff[c][n] = rowv * 128 + (((4 * c + lg) ^ (rowv & 7)) << 4);
        }
    }

    const bf16_t* kptr[2];
    const bf16_t* vptr[2];
    char* kdst[2];
    char* vdst[2];
    #pragma unroll
    for (int it = 0; it < 2; ++it) {
        const int idx = it * 256 + tid;
        const int row = idx >> 3, slot = idx & 7;
        kptr[it] = kg + ((size_t)((b << 11) + row) << 10) + h * 64 + (slot ^ fk(row)) * 8;
        vptr[it] = vg + (((size_t)bh * 64 + row) << 11) + (slot ^ (row & 7)) * 8;
        kdst[it] = (char*)ks + idx * 16;
        vdst[it] = (char*)vts + idx * 16;
    }

    f32x4 accO[2][4] = {};
    f32x4 accL[2] = {};

    auto STAGE = [&](int buf) {
        const int nb = buf << 13;
        #pragma unroll
        for (int it = 0; it < 2; ++it) {
            gload_lds16(kptr[it], kdst[it] + nb);
            gload_lds16(vptr[it], vdst[it] + nb);
            kptr[it] += (size_t)64 << 10;
            vptr[it] += 64;
        }
    };

    auto COMPUTE = [&](int buf, int t0, bool tl) {
        const char* ksb = (const char*)ks + (buf << 13);
        const char* vsb = (const char*)vts + (buf << 13);
        #pragma unroll
        for (int c = 0; c < 2; ++c) {
            unsigned int pw0[4], pw1[4];
            #pragma unroll
            for (int kf1 = 0; kf1 < 2; ++kf1) {
                bf16x8 a0 = ldsx8(ksb + koff[c][kf1][0]);
                bf16x8 a1 = ldsx8(ksb + koff[c][kf1][1]);
                f32x4 z0 = {}, z1 = {};
                if (tl) {
                    const int keyb = t0 + c * 32 + 8 * lg + 4 * kf1;
                    f32x4 bias;
                    #pragma unroll
                    for (int r = 0; r < 4; ++r)
                        bias[r] = (keyb + r < nk) ? 0.0f : -1.0e9f;
                    z0 = bias; z1 = bias;
                }
                __builtin_amdgcn_s_setprio(1);
                z0 = __builtin_amdgcn_mfma_f32_16x16x32_bf16(a0, aq[0][0], z0, 0, 0, 0);
                z0 = __builtin_amdgcn_mfma_f32_16x16x32_bf16(a1, aq[0][1], z0, 0, 0, 0);
                z1 = __builtin_amdgcn_mfma_f32_16x16x32_bf16(a0, aq[1][0], z1, 0, 0, 0);
                z1 = __builtin_amdgcn_mfma_f32_16x16x32_bf16(a1, aq[1][1], z1, 0, 0, 0);
                __builtin_amdgcn_s_setprio(0);
                const float p00 = __builtin_amdgcn_exp2f(z0[0]);
                const float p01 = __builtin_amdgcn_exp2f(z0[1]);
                const float p02 = __builtin_amdgcn_exp2f(z0[2]);
                const float p03 = __builtin_amdgcn_exp2f(z0[3]);
                const float p10 = __builtin_amdgcn_exp2f(z1[0]);
                const float p11 = __builtin_amdgcn_exp2f(z1[1]);
                const float p12 = __builtin_amdgcn_exp2f(z1[2]);
                const float p13 = __builtin_amdgcn_exp2f(z1[3]);
                pw0[2 * kf1]     = bf16bits(p00) | ((unsigned)bf16bits(p01) << 16);
                pw0[2 * kf1 + 1] = bf16bits(p02) | ((unsigned)bf16bits(p03) << 16);
                pw1[2 * kf1]     = bf16bits(p10) | ((unsigned)bf16bits(p11) << 16);
                pw1[2 * kf1 + 1] = bf16bits(p12) | ((unsigned)bf16bits(p13) << 16);
            }
            uint4 pk0 = {pw0[0], pw0[1], pw0[2], pw0[3]};
            uint4 pk1 = {pw1[0], pw1[1], pw1[2], pw1[3]};
            const bf16x8 pa0 = __builtin_bit_cast(bf16x8, pk0);
            const bf16x8 pa1 = __builtin_bit_cast(bf16x8, pk1);

            __builtin_amdgcn_s_setprio(1);
            #pragma unroll
            for (int n = 0; n < 4; ++n) {
                bf16x8 av = ldsx8(vsb + voff[c][n]);
                accO[0][n] = __builtin_amdgcn_mfma_f32_16x16x32_bf16(av, pa0, accO[0][n], 0, 0, 0);
                accO[1][n] = __builtin_amdgcn_mfma_f32_16x16x32_bf16(av, pa1, accO[1][n], 0, 0, 0);
            }
            accL[0] = __builtin_amdgcn_mfma_f32_16x16x32_bf16(onesf, pa0, accL[0], 0, 0, 0);
            accL[1] = __builtin_amdgcn_mfma_f32_16x16x32_bf16(onesf, pa1, accL[1], 0, 0, 0);
            __builtin_amdgcn_s_setprio(0);
        }
    };

    STAGE(0);
    __syncthreads();

    int cur = 0;
    for (int t = 0; t < ntiles; ++t) {
        if (t + 1 < ntiles) STAGE(cur ^ 1);
        COMPUTE(cur, t * 64, hastail && (t == ntiles - 1));
        __syncthreads();
        cur ^= 1;
    }

    #pragma unroll
    for (int f = 0; f < 2; ++f) {
        const float inv = 1.0f / __shfl(accL[f][0], lr);
        bf16_t* obase = ctx + ((size_t)(b * S_ + q0w + f * 16 + lr) << 10) + h * 64;
        #pragma unroll
        for (int n = 0; n < 4; ++n) {
            ushort4 o;
            o.x = bf16bits(accO[f][n][0] * inv);
            o.y = bf16bits(accO[f][n][1] * inv);
            o.z = bf16bits(accO[f][n][2] * inv);
            o.w = bf16bits(accO[f][n][3] * inv);
            *(ushort4*)(obase + n * 16 + lg * 4) = o;
        }
    }
}

// ---------------------------------------------------------------------------
// Fused prep: x cast + all 5 weight transpose/converts + bqs = bq*QSCALE.
// ---------------------------------------------------------------------------
__global__ __launch_bounds__(256) void prep_all(
    const float* __restrict__ x, bf16_t* __restrict__ xb,
    const float* __restrict__ Wq, const float* __restrict__ Wk,
    const float* __restrict__ Wv, bf16_t* __restrict__ WqkvT,
    const float* __restrict__ Wo, bf16_t* __restrict__ WoT,
    const float* __restrict__ W1, bf16_t* __restrict__ W1T,
    const float* __restrict__ W2, bf16_t* __restrict__ W2T,
    const float* __restrict__ bq, float* __restrict__ bqs)
{
    __shared__ float t[32][33];
    const int tid = threadIdx.x;
    int bid = blockIdx.x;

    if (bid < 4096) {               // x f32 -> bf16, 8 per thread
        int i = bid * 256 + tid;
        float4 a = ((const float4*)x)[i * 2];
        float4 b = ((const float4*)x)[i * 2 + 1];
        unsigned int p0 = bf16bits(a.x) | ((unsigned)bf16bits(a.y) << 16);
        unsigned int p1 = bf16bits(a.z) | ((unsigned)bf16bits(a.w) << 16);
        unsigned int p2 = bf16bits(b.x) | ((unsigned)bf16bits(b.y) << 16);
        unsigned int p3 = bf16bits(b.z) | ((unsigned)bf16bits(b.w) << 16);
        uint4 o = {p0, p1, p2, p3};
        ((uint4*)xb)[i] = o;
        return;
    }
    bid -= 4096;

    if (bid == 4224) {              // bqs = bq * QSCALE (1024 floats)
        #pragma unroll
        for (int j = 0; j < 4; ++j)
            bqs[tid * 4 + j] = bq[tid * 4 + j] * QSCALE;
        return;
    }

    const float* in; bf16_t* out;
    int R, C, c0, r0;
    float scale = 1.0f;
    if (bid < 3072) {               // Wq/Wk/Wv [16][1024][64] -> per-head [64][1024]
        const int p = bid >> 10, r = bid & 1023;
        const int z = r >> 6, rem = r & 63;
        in  = (p == 0 ? Wq : p == 1 ? Wk : Wv) + z * 65536;
        out = WqkvT + p * 1048576 + z * 65536;
        R = 1024; C = 64;
        c0 = (rem & 1) * 32; r0 = (rem >> 1) * 32;
        if (p == 0) scale = QSCALE;
    } else if (bid < 4096) {        // Wo [1024][1024]
        const int r = bid - 3072;
        in = Wo; out = WoT; R = 1024; C = 1024;
        c0 = (r & 31) * 32; r0 = (r >> 5) * 32;
    } else if (bid < 4160) {        // W1 [1024][64]
        const int r = bid - 4096;
        in = W1; out = W1T; R = 1024; C = 64;
        c0 = (r & 1) * 32; r0 = (r >> 1) * 32;
    } else {                        // W2 [64][1024]
        const int r = bid - 4160;
        in = W2; out = W2T; R = 64; C = 1024;
        c0 = (r & 31) * 32; r0 = (r >> 5) * 32;
    }

    {
        int rr = tid >> 3, c4 = (tid & 7) * 4;
        float4 v = *(const float4*)&in[(size_t)(r0 + rr) * C + c0 + c4];
        t[rr][c4 + 0] = v.x * scale;
        t[rr][c4 + 1] = v.y * scale;
        t[rr][c4 + 2] = v.z * scale;
        t[rr][c4 + 3] = v.w * scale;
    }
    __syncthreads();
    {
        int c = tid >> 3, r4 = (tid & 7) * 4;
        ushort4 o;
        o.x = bf16bits(t[r4 + 0][c]);
        o.y = bf16bits(t[r4 + 1][c]);
        o.z = bf16bits(t[r4 + 2][c]);
        o.w = bf16bits(t[r4 + 3][c]);
        *(ushort4*)(out + (size_t)(c0 + c) * R + r0 + r4) = o;
    }
}

// ---------------------------------------------------------------------------
// Row LayerNorm over 1024. InT: float or bf16; OutT: float or bf16.
// ---------------------------------------------------------------------------
template<typename InT, typename OutT>
__global__ __launch_bounds__(256) void ln_kernel(
    const InT* __restrict__ in, const float* __restrict__ g,
    const float* __restrict__ bta, OutT* __restrict__ out)
{
    const int row = blockIdx.x;
    const int tid = threadIdx.x;

    float x0, x1, x2, x3;
    if constexpr (sizeof(InT) == 4) {
        float4 xv = ((const float4*)(in + (size_t)row * E_))[tid];
        x0 = xv.x; x1 = xv.y; x2 = xv.z; x3 = xv.w;
    } else {
        ushort4 xv = *(const ushort4*)((const bf16_t*)in + (size_t)row * E_ + tid * 4);
        x0 = (float)__builtin_bit_cast(bf16_t, xv.x);
        x1 = (float)__builtin_bit_cast(bf16_t, xv.y);
        x2 = (float)__builtin_bit_cast(bf16_t, xv.z);
        x3 = (float)__builtin_bit_cast(bf16_t, xv.w);
    }
    float s  = x0 + x1 + x2 + x3;
    float sq = x0 * x0 + x1 * x1 + x2 * x2 + x3 * x3;
    #pragma unroll
    for (int off = 32; off > 0; off >>= 1) {
        s  += __shfl_down(s, off);
        sq += __shfl_down(sq, off);
    }
    __shared__ float ss[4], ssq[4];
    if ((tid & 63) == 0) { ss[tid >> 6] = s; ssq[tid >> 6] = sq; }
    __syncthreads();
    s  = ss[0] + ss[1] + ss[2] + ss[3];
    sq = ssq[0] + ssq[1] + ssq[2] + ssq[3];

    const float mean = s * (1.0f / E_);
    const float var  = sq * (1.0f / E_) - mean * mean;
    const float rstd = rsqrtf(var + 1e-5f);

    float4 gv = ((const float4*)g)[tid];
    float4 bv = ((const float4*)bta)[tid];
    float o0 = (x0 - mean) * rstd * gv.x + bv.x;
    float o1 = (x1 - mean) * rstd * gv.y + bv.y;
    float o2 = (x2 - mean) * rstd * gv.z + bv.z;
    float o3 = (x3 - mean) * rstd * gv.w + bv.w;
    if constexpr (sizeof(OutT) == 4) {
        float4 o = {o0, o1, o2, o3};
        ((float4*)((float*)out + (size_t)row * E_))[tid] = o;
    } else {
        ushort4 o;
        o.x = bf16bits(o0); o.y = bf16bits(o1);
        o.z = bf16bits(o2); o.w = bf16bits(o3);
        *(ushort4*)((bf16_t*)out + (size_t)row * E_ + tid * 4) = o;
    }
}

// ---------------------------------------------------------------------------
extern "C" void kernel_launch(void* const* d_in, const int* in_sizes, int n_in,
                              void* d_out, int out_size, void* d_ws, size_t ws_size,
                              hipStream_t stream)
{
    const float* x    = (const float*)d_in[0];
    const int*   mask = (const int*)d_in[1];
    const float* Wq   = (const float*)d_in[2];
    const float* bq   = (const float*)d_in[3];
    const float* Wk   = (const float*)d_in[4];
    const float* bk   = (const float*)d_in[5];
    const float* Wv   = (const float*)d_in[6];
    const float* bv   = (const float*)d_in[7];
    const float* Wo   = (const float*)d_in[8];
    const float* bo   = (const float*)d_in[9];
    const float* g1   = (const float*)d_in[10];
    const float* b1   = (const float*)d_in[11];
    const float* W1   = (const float*)d_in[12];
    const float* c1   = (const float*)d_in[13];
    const float* W2   = (const float*)d_in[14];
    const float* c2   = (const float*)d_in[15];
    const float* g2   = (const float*)d_in[16];
    const float* b2   = (const float*)d_in[17];

    char* W = (char*)d_ws;                       // peak ~92.6 MB
    bf16_t* xb    = (bf16_t*)(W + 0);            // 16 MB
    bf16_t* WqkvT = (bf16_t*)(W + 16777216);     //  6 MB [3][1024 n][1024 k]
    bf16_t* WoT   = (bf16_t*)(W + 23068672);     //  2 MB
    bf16_t* W1T   = (bf16_t*)(W + 25165824);     //  128K
    bf16_t* W2T   = (bf16_t*)(W + 25296896);     //  128K
    bf16_t* qbuf  = (bf16_t*)(W + 25427968);     // 16 MB [b,s,h,d]
    bf16_t* kbuf  = (bf16_t*)(W + 42205184);     // 16 MB [b][ci][h,d] compact
    bf16_t* vtc   = (bf16_t*)(W + 58982400);     // 16 MB [bh][d][ci] compact
    bf16_t* ctx   = (bf16_t*)(W + 75759616);     // 16 MB
    bf16_t* t1b   = (bf16_t*)(W + 25427968);     // over qbuf (dead after attn)
    bf16_t* hb    = (bf16_t*)(W + 42205184);     // over kbuf (dead after attn)
    bf16_t* f1b   = (bf16_t*)(W + 0);            // over xb (dead after GEMMs)
    bf16_t* f2b   = (bf16_t*)(W + 58982400);     // over vtc (dead after attn)
    int*    sidx  = (int*)(W + 92536832);        // 32 KB
    int*    nkv   = (int*)(W + 92569600);        // 16 B (pad to 64)
    float*  bqs   = (float*)(W + 92569664);      // 4 KB
    float*  out   = (float*)d_out;

    // fused prep (1/sqrt(S)*log2e folded into Wq and bqs)
    prep_all<<<8321, 256, 0, stream>>>(x, xb, Wq, Wk, Wv, WqkvT,
                                       Wo, WoT, W1, W1T, W2, W2T, bq, bqs);

    // mask scan -> sidx / nkv
    compact_mask<<<4, 256, 0, stream>>>(mask, sidx, nkv);

    // Q projection [8192 x 1024 x 1024] -> qbuf
    gemm_bf16<128, 128, 0><<<dim3(8, 64), 256, 0, stream>>>(
        xb, WqkvT, qbuf, nullptr, nullptr, bqs, nullptr, nullptr, nullptr,
        M_, 1024, 1024);

    // KV projection over compacted rows only -> kbuf / vtc (direct compact)
    gemm_bf16<128, 128, 2><<<dim3(16, 64), 256, 0, stream>>>(
        xb, WqkvT + (1 << 20), nullptr, kbuf, vtc, bk, bv, sidx, nkv,
        M_, 2048, 1024);

    // attention over compacted keys
    attn_mfma<<<dim3(1024), 256, 0, stream>>>(qbuf, kbuf, vtc, nkv, ctx);

    // output projection -> bf16 t1
    gemm_bf16<128, 128, 0><<<dim3(8, 64), 256, 0, stream>>>(
        ctx, WoT, t1b, nullptr, nullptr, bo, nullptr, nullptr, nullptr,
        M_, 1024, 1024);

    ln_kernel<bf16_t, bf16_t><<<8192, 256, 0, stream>>>(t1b, g1, b1, hb);

    // FFN1 (N=64) + exact GELU -> bf16
    gemm_bf16<32, 64, 1><<<dim3(1, 256), 256, 0, stream>>>(
        hb, W1T, f1b, nullptr, nullptr, c1, nullptr, nullptr, nullptr,
        M_, 64, 1024);

    // FFN2 (K=64) -> bf16
    gemm_bf16<128, 128, 0><<<dim3(8, 64), 256, 0, stream>>>(
        f1b, W2T, f2b, nullptr, nullptr, c2, nullptr, nullptr, nullptr,
        M_, 1024, 64);

    ln_kernel<bf16_t, float><<<8192, 256, 0, stream>>>(f2b, g2, b2, out);
}

// Round 13
// 199.652 us; speedup vs baseline: 1.2058x; 1.0548x over previous
//
#include <hip/hip_runtime.h>
#include <math.h>

#define B_ 4
#define S_ 2048
#define E_ 1024
#define H_ 16
#define D_ 64
#define M_ (B_*S_)
// 1/sqrt(2048) * log2(e): scale folded into Wq/bq so softmax uses exp2 directly
#define QSCALE (0.022097086912079608f * 1.4426950408889634f)

typedef __bf16 bf16_t;
typedef __bf16 bf16x8 __attribute__((ext_vector_type(8)));
typedef float  f32x4  __attribute__((ext_vector_type(4)));

// async global->LDS, 16B per lane. LDS dest must be linear (base + lane*16).
__device__ __forceinline__ void gload_lds16(const void* g, void* l) {
    __builtin_amdgcn_global_load_lds(
        (const __attribute__((address_space(1))) void*)g,
        (__attribute__((address_space(3))) void*)l, 16, 0, 0);
}
__device__ __forceinline__ bf16x8 ldsx8(const void* p) {
    return __builtin_bit_cast(bf16x8, *(const uint4*)p);
}
__device__ __forceinline__ unsigned short bf16bits(float x) {
    return __builtin_bit_cast(unsigned short, (bf16_t)x);
}
// counted waitcnt: allow N newest vector-mem ops to stay in flight
template<int N> __device__ __forceinline__ void waitv() {
    if constexpr (N == 8)      asm volatile("s_waitcnt vmcnt(8) lgkmcnt(0)" ::: "memory");
    else if constexpr (N == 4) asm volatile("s_waitcnt vmcnt(4) lgkmcnt(0)" ::: "memory");
    else if constexpr (N == 3) asm volatile("s_waitcnt vmcnt(3) lgkmcnt(0)" ::: "memory");
    else                       asm volatile("s_waitcnt vmcnt(0) lgkmcnt(0)" ::: "memory");
}
// swizzle for K-tile QK^T A-frag read rows {32c + 8a + 4kf + b}: f = (b + 2a) & 7
__device__ __forceinline__ int fk(int row) { return ((row & 3) + 2 * ((row >> 3) & 3)) & 7; }

// ---------------------------------------------------------------------------
// bf16 MFMA GEMM, C = A[M,K] x Bt[N,K]^T. BK=64, LDS double-buffered,
// counted-vmcnt barriers (loads stay in flight across s_barrier).
// MODE 0: bf16 out + bias. MODE 1: bf16 out + bias + exact GELU.
// MODE 3: merged Q + compacted-KV projection (grid 1536 flat):
//   blocks 0-511:    Q [8192x1024] -> ob0, bias0 (pre-scaled bqs)
//   blocks 512-1535: KV over compacted rows (sidx gather, early-exit);
//     cols 0-1023 = K (+bias1) -> ob1[b][ci][nn]; cols 1024-2047 = V (+bias2)
//     -> ob2[bh][d][ci] (4 consecutive ci).
// ---------------------------------------------------------------------------
template<int BM, int BN, int MODE>
__global__ __launch_bounds__(256) void gemm_bf16(
    const bf16_t* __restrict__ A, const bf16_t* __restrict__ Bt,
    bf16_t* __restrict__ ob0, bf16_t* __restrict__ ob1, bf16_t* __restrict__ ob2,
    const float* __restrict__ bias0, const float* __restrict__ bias1,
    const float* __restrict__ bias2,
    const int* __restrict__ sidx, const int* __restrict__ nkv,
    int M, int N, int K)
{
    constexpr int FM = BM / 32, FN = BN / 32;
    constexpr int NL = BM / 32 + BN / 32;    // gload_lds per thread per K-step
    __shared__ bf16_t As[2][BM * 64];
    __shared__ bf16_t Bs[2][BN * 64];

    const int tid = threadIdx.x;
    const int w   = tid >> 6;
    const int wr  = w >> 1, wc = w & 1;
    const int lr  = tid & 15;
    const int lg  = (tid >> 4) & 3;

    // XCD-bijective block swizzle: 8 contiguous chunks, one per XCD
    const int nwg  = gridDim.x * gridDim.y;
    int bidf = blockIdx.y * gridDim.x + blockIdx.x;
    bidf = (bidf & 7) * (nwg >> 3) + (bidf >> 3);

    int bm, bn;
    bool isQ = true;
    const bf16_t* Bp = Bt;
    if constexpr (MODE == 3) {
        isQ = bidf < 512;
        if (isQ) {
            bm = (bidf >> 3) * 128;
            bn = (bidf & 7) * 128;
        } else {
            const int kv = bidf - 512;
            bm = (kv >> 4) * 128;
            bn = (kv & 15) * 128;
            Bp = Bt + (1 << 20);
        }
    } else {
        bm = (bidf / gridDim.x) * BM;
        bn = (bidf % gridDim.x) * BN;
    }

    // A-row mapping (MODE3 KV: gathered via sidx, with early exit)
    int arow[FM];
    {
        if constexpr (MODE == 3) {
            const int b2 = bm >> 11, rbase = bm & 2047;
            if (!isQ) {
                const int nkp128 = (nkv[b2] + 127) & ~127;
                if (rbase >= nkp128) return;
            }
            #pragma unroll
            for (int i = 0; i < FM; ++i) {
                const int row = (i * 256 + tid) >> 3;
                arow[i] = isQ ? (bm + row)
                              : ((b2 << 11) + sidx[(b2 << 11) + rbase + row]);
            }
        } else {
            #pragma unroll
            for (int i = 0; i < FM; ++i)
                arow[i] = bm + ((i * 256 + tid) >> 3);
        }
    }

    f32x4 acc[FM][FN] = {};

    auto STAGE = [&](int buf, int kk) {
        #pragma unroll
        for (int i = 0; i < BM / 32; ++i) {
            int idx = i * 256 + tid;
            int row = idx >> 3, slot = idx & 7;
            gload_lds16(A + (size_t)arow[i] * K + kk + (slot ^ (row & 7)) * 8,
                        (char*)As[buf] + idx * 16);
        }
        #pragma unroll
        for (int i = 0; i < BN / 32; ++i) {
            int idx = i * 256 + tid;
            int row = idx >> 3, slot = idx & 7;
            gload_lds16(Bp + (size_t)(bn + row) * K + kk + (slot ^ (row & 7)) * 8,
                        (char*)Bs[buf] + idx * 16);
        }
    };

    auto COMPUTE = [&](int buf) {
        #pragma unroll
        for (int h = 0; h < 2; ++h) {
            bf16x8 af[FM], bfr[FN];
            #pragma unroll
            for (int m = 0; m < FM; ++m) {
                int row = wr * (BM / 2) + m * 16 + lr;
                af[m] = ldsx8((char*)As[buf] + row * 128 + (((4 * h + lg) ^ (row & 7)) << 4));
            }
            #pragma unroll
            for (int n = 0; n < FN; ++n) {
                int col = wc * (BN / 2) + n * 16 + lr;
                bfr[n] = ldsx8((char*)Bs[buf] + col * 128 + (((4 * h + lg) ^ (col & 7)) << 4));
            }
            #pragma unroll
            for (int m = 0; m < FM; ++m)
                #pragma unroll
                for (int n = 0; n < FN; ++n)
                    acc[m][n] = __builtin_amdgcn_mfma_f32_16x16x32_bf16(
                        af[m], bfr[n], acc[m][n], 0, 0, 0);
        }
    };

    STAGE(0, 0);
    int cur = 0;
    for (int kk = 0; kk < K; kk += 64) {
        const bool hasnext = (kk + 64 < K);
        if (hasnext) {
            STAGE(cur ^ 1, kk + 64);
            waitv<NL>();
        } else {
            waitv<0>();
        }
        __builtin_amdgcn_s_barrier();
        COMPUTE(cur);
        __builtin_amdgcn_s_barrier();
        cur ^= 1;
    }

    #pragma unroll
    for (int n = 0; n < FN; ++n) {
        if constexpr (MODE == 3) {
            if (isQ) {
                const int gcol = bn + wc * 64 + n * 16 + lr;
                const float bvl = bias0[gcol];
                #pragma unroll
                for (int m = 0; m < FM; ++m)
                    #pragma unroll
                    for (int r = 0; r < 4; ++r) {
                        const int grow = bm + wr * 64 + m * 16 + lg * 4 + r;
                        ob0[((size_t)grow << 10) + gcol] = (bf16_t)(acc[m][n][r] + bvl);
                    }
            } else {
                const int gcol = bn + wc * 64 + n * 16 + lr;
                const int p = gcol >> 10, nn = gcol & 1023;
                const int b2 = bm >> 11;
                const float bvl = p ? bias2[nn] : bias1[nn];
                #pragma unroll
                for (int m = 0; m < FM; ++m) {
                    const int ci0 = (bm & 2047) + wr * 64 + m * 16 + lg * 4;
                    if (p) {    // V^T: 4 consecutive ci
                        ushort4 o;
                        o.x = bf16bits(acc[m][n][0] + bvl);
                        o.y = bf16bits(acc[m][n][1] + bvl);
                        o.z = bf16bits(acc[m][n][2] + bvl);
                        o.w = bf16bits(acc[m][n][3] + bvl);
                        *(ushort4*)(ob2 + ((((size_t)b2 << 10) + nn) << 11) + ci0) = o;
                    } else {    // K compact rows
                        #pragma unroll
                        for (int r = 0; r < 4; ++r)
                            ob1[((size_t)((b2 << 11) + ci0 + r) << 10) + nn] =
                                (bf16_t)(acc[m][n][r] + bvl);
                    }
                }
            }
        } else {
            const int gcol = bn + wc * (BN / 2) + n * 16 + lr;
            const float bvl = bias0[gcol];
            #pragma unroll
            for (int m = 0; m < FM; ++m)
                #pragma unroll
                for (int r = 0; r < 4; ++r) {
                    const int grow = bm + wr * (BM / 2) + m * 16 + lg * 4 + r;
                    float v = acc[m][n][r] + bvl;
                    if constexpr (MODE == 1)
                        v = 0.5f * v * (1.0f + erff(v * 0.70710678118654752f));
                    ob0[(size_t)grow * N + gcol] = (bf16_t)v;
                }
        }
    }
}

// ---------------------------------------------------------------------------
// Mask compaction: order-preserving scan -> sidx[b][ci] = original s,
// padded with 0 up to the next multiple of 128. nkv[b] = survivor count.
// ---------------------------------------------------------------------------
__global__ __launch_bounds__(256) void compact_mask(
    const int* __restrict__ mask, int* __restrict__ sidx, int* __restrict__ nkv)
{
    __shared__ int wsum[4];
    const int b = blockIdx.x;
    const int tid = threadIdx.x;
    const int lane = tid & 63, wv = tid >> 6;
    const int base = tid * 8;

    int m[8], loc[8];
    int cnt = 0;
    #pragma unroll
    for (int j = 0; j < 8; ++j) {
        m[j] = mask[b * S_ + base + j];
        loc[j] = cnt;
        cnt += (m[j] != 0);
    }
    int incl = cnt;
    #pragma unroll
    for (int off = 1; off < 64; off <<= 1) {
        int t = __shfl_up(incl, off);
        if (lane >= off) incl += t;
    }
    if (lane == 63) wsum[wv] = incl;
    const int excl_lane = incl - cnt;
    __syncthreads();
    int wbase = 0;
    for (int i = 0; i < wv; ++i) wbase += wsum[i];
    const int total = wsum[0] + wsum[1] + wsum[2] + wsum[3];
    if (tid == 0) nkv[b] = total;
    const int tbase = wbase + excl_lane;
    #pragma unroll
    for (int j = 0; j < 8; ++j)
        if (m[j]) sidx[b * S_ + tbase + loc[j]] = base + j;

    const int nkp = (total + 127) & ~127;
    for (int c = total + tid; c < nkp; c += 256)
        sidx[b * S_ + c] = 0;
}

// ---------------------------------------------------------------------------
// MFMA flash attention over COMPACTED keys. Counted-vmcnt double-buffer
// (loads stay in flight across barriers). Zero-shuffle P path, 4 waves x
// 32 q-rows, KVBLK=64. Full tiles: z init = 0. Tail tile: register bias.
// L via ones-row MFMA; exp2-domain scores. 8 bh per XCD.
// ---------------------------------------------------------------------------
__global__ __launch_bounds__(256) void attn_mfma(
    const bf16_t* __restrict__ qg, const bf16_t* __restrict__ kg,
    const bf16_t* __restrict__ vg, const int* __restrict__ nkv,
    bf16_t* __restrict__ ctx)
{
    __shared__ bf16_t ks[2][64 * 64];   // [key][d] 128B rows, fk-swizzled
    __shared__ bf16_t vts[2][64 * 64];  // [d][key] 128B rows, row&7-swizzled

    const int tid = threadIdx.x;
    const int w   = tid >> 6;
    const int lr  = tid & 15;
    const int lg  = (tid >> 4) & 3;

    const int bid = blockIdx.x;
    const int xcd = bid & 7, kidx = bid >> 3;        // kidx in [0,128)
    const int bh  = xcd * 8 + (kidx >> 4);           // 8 bh per XCD
    const int xq  = kidx & 15;                       // 16 q-blocks of 128
    const int b   = bh >> 4, h = bh & 15;
    const int q0w = xq * 128 + w * 32;               // wave owns 32 q-rows

    const int nk = nkv[b];
    const int ntiles = (nk + 63) >> 6;
    const bool hastail = (nk & 63) != 0;

    bf16x8 aq[2][2];
    #pragma unroll
    for (int f = 0; f < 2; ++f) {
        const bf16_t* qp = qg + ((size_t)(b * S_ + q0w + f * 16 + lr) << 10) + h * 64 + lg * 8;
        aq[f][0] = ldsx8(qp);
        aq[f][1] = ldsx8(qp + 32);
    }

    bf16x8 onesf;
    {
        bf16_t o1 = (bf16_t)((lr == 0) ? 1.0f : 0.0f);
        #pragma unroll
        for (int j = 0; j < 8; ++j) onesf[j] = o1;
    }

    int koff[2][2][2], voff[2][4];
    #pragma unroll
    for (int c = 0; c < 2; ++c) {
        #pragma unroll
        for (int kf1 = 0; kf1 < 2; ++kf1) {
            const int row = c * 32 + 8 * (lr >> 2) + 4 * kf1 + (lr & 3);
            const int f = fk(row);
            koff[c][kf1][0] = row * 128 + ((lg ^ f) << 4);
            koff[c][kf1][1] = row * 128 + (((4 + lg) ^ f) << 4);
        }
        #pragma unroll
        for (int n = 0; n < 4; ++n) {
            const int rowv = n * 16 + lr;
            voff[c][n] = rowv * 128 + (((4 * c + lg) ^ (rowv & 7)) << 4);
        }
    }

    const bf16_t* kptr[2];
    const bf16_t* vptr[2];
    char* kdst[2];
    char* vdst[2];
    #pragma unroll
    for (int it = 0; it < 2; ++it) {
        const int idx = it * 256 + tid;
        const int row = idx >> 3, slot = idx & 7;
        kptr[it] = kg + ((size_t)((b << 11) + row) << 10) + h * 64 + (slot ^ fk(row)) * 8;
        vptr[it] = vg + (((size_t)bh * 64 + row) << 11) + (slot ^ (row & 7)) * 8;
        kdst[it] = (char*)ks + idx * 16;
        vdst[it] = (char*)vts + idx * 16;
    }

    f32x4 accO[2][4] = {};
    f32x4 accL[2] = {};

    auto STAGE = [&](int buf) {
        const int nb = buf << 13;
        #pragma unroll
        for (int it = 0; it < 2; ++it) {
            gload_lds16(kptr[it], kdst[it] + nb);
            gload_lds16(vptr[it], vdst[it] + nb);
            kptr[it] += (size_t)64 << 10;
            vptr[it] += 64;
        }
    };

    auto COMPUTE = [&](int buf, int t0, bool tl) {
        const char* ksb = (const char*)ks + (buf << 13);
        const char* vsb = (const char*)vts + (buf << 13);
        #pragma unroll
        for (int c = 0; c < 2; ++c) {
            unsigned int pw0[4], pw1[4];
            #pragma unroll
            for (int kf1 = 0; kf1 < 2; ++kf1) {
                bf16x8 a0 = ldsx8(ksb + koff[c][kf1][0]);
                bf16x8 a1 = ldsx8(ksb + koff[c][kf1][1]);
                f32x4 z0 = {}, z1 = {};
                if (tl) {
                    const int keyb = t0 + c * 32 + 8 * lg + 4 * kf1;
                    f32x4 bias;
                    #pragma unroll
                    for (int r = 0; r < 4; ++r)
                        bias[r] = (keyb + r < nk) ? 0.0f : -1.0e9f;
                    z0 = bias; z1 = bias;
                }
                __builtin_amdgcn_s_setprio(1);
                z0 = __builtin_amdgcn_mfma_f32_16x16x32_bf16(a0, aq[0][0], z0, 0, 0, 0);
                z0 = __builtin_amdgcn_mfma_f32_16x16x32_bf16(a1, aq[0][1], z0, 0, 0, 0);
                z1 = __builtin_amdgcn_mfma_f32_16x16x32_bf16(a0, aq[1][0], z1, 0, 0, 0);
                z1 = __builtin_amdgcn_mfma_f32_16x16x32_bf16(a1, aq[1][1], z1, 0, 0, 0);
                __builtin_amdgcn_s_setprio(0);
                const float p00 = __builtin_amdgcn_exp2f(z0[0]);
                const float p01 = __builtin_amdgcn_exp2f(z0[1]);
                const float p02 = __builtin_amdgcn_exp2f(z0[2]);
                const float p03 = __builtin_amdgcn_exp2f(z0[3]);
                const float p10 = __builtin_amdgcn_exp2f(z1[0]);
                const float p11 = __builtin_amdgcn_exp2f(z1[1]);
                const float p12 = __builtin_amdgcn_exp2f(z1[2]);
                const float p13 = __builtin_amdgcn_exp2f(z1[3]);
                pw0[2 * kf1]     = bf16bits(p00) | ((unsigned)bf16bits(p01) << 16);
                pw0[2 * kf1 + 1] = bf16bits(p02) | ((unsigned)bf16bits(p03) << 16);
                pw1[2 * kf1]     = bf16bits(p10) | ((unsigned)bf16bits(p11) << 16);
                pw1[2 * kf1 + 1] = bf16bits(p12) | ((unsigned)bf16bits(p13) << 16);
            }
            uint4 pk0 = {pw0[0], pw0[1], pw0[2], pw0[3]};
            uint4 pk1 = {pw1[0], pw1[1], pw1[2], pw1[3]};
            const bf16x8 pa0 = __builtin_bit_cast(bf16x8, pk0);
            const bf16x8 pa1 = __builtin_bit_cast(bf16x8, pk1);

            __builtin_amdgcn_s_setprio(1);
            #pragma unroll
            for (int n = 0; n < 4; ++n) {
                bf16x8 av = ldsx8(vsb + voff[c][n]);
                accO[0][n] = __builtin_amdgcn_mfma_f32_16x16x32_bf16(av, pa0, accO[0][n], 0, 0, 0);
                accO[1][n] = __builtin_amdgcn_mfma_f32_16x16x32_bf16(av, pa1, accO[1][n], 0, 0, 0);
            }
            accL[0] = __builtin_amdgcn_mfma_f32_16x16x32_bf16(onesf, pa0, accL[0], 0, 0, 0);
            accL[1] = __builtin_amdgcn_mfma_f32_16x16x32_bf16(onesf, pa1, accL[1], 0, 0, 0);
            __builtin_amdgcn_s_setprio(0);
        }
    };

    STAGE(0);
    int cur = 0;
    for (int t = 0; t < ntiles; ++t) {
        if (t + 1 < ntiles) {
            STAGE(cur ^ 1);
            waitv<4>();
        } else {
            waitv<0>();
        }
        __builtin_amdgcn_s_barrier();
        COMPUTE(cur, t * 64, hastail && (t == ntiles - 1));
        __builtin_amdgcn_s_barrier();
        cur ^= 1;
    }

    #pragma unroll
    for (int f = 0; f < 2; ++f) {
        const float inv = 1.0f / __shfl(accL[f][0], lr);
        bf16_t* obase = ctx + ((size_t)(b * S_ + q0w + f * 16 + lr) << 10) + h * 64;
        #pragma unroll
        for (int n = 0; n < 4; ++n) {
            ushort4 o;
            o.x = bf16bits(accO[f][n][0] * inv);
            o.y = bf16bits(accO[f][n][1] * inv);
            o.z = bf16bits(accO[f][n][2] * inv);
            o.w = bf16bits(accO[f][n][3] * inv);
            *(ushort4*)(obase + n * 16 + lg * 4) = o;
        }
    }
}

// ---------------------------------------------------------------------------
// Fused prep: x cast + all 5 weight transpose/converts + bqs = bq*QSCALE.
// ---------------------------------------------------------------------------
__global__ __launch_bounds__(256) void prep_all(
    const float* __restrict__ x, bf16_t* __restrict__ xb,
    const float* __restrict__ Wq, const float* __restrict__ Wk,
    const float* __restrict__ Wv, bf16_t* __restrict__ WqkvT,
    const float* __restrict__ Wo, bf16_t* __restrict__ WoT,
    const float* __restrict__ W1, bf16_t* __restrict__ W1T,
    const float* __restrict__ W2, bf16_t* __restrict__ W2T,
    const float* __restrict__ bq, float* __restrict__ bqs)
{
    __shared__ float t[32][33];
    const int tid = threadIdx.x;
    int bid = blockIdx.x;

    if (bid < 4096) {               // x f32 -> bf16, 8 per thread
        int i = bid * 256 + tid;
        float4 a = ((const float4*)x)[i * 2];
        float4 b = ((const float4*)x)[i * 2 + 1];
        unsigned int p0 = bf16bits(a.x) | ((unsigned)bf16bits(a.y) << 16);
        unsigned int p1 = bf16bits(a.z) | ((unsigned)bf16bits(a.w) << 16);
        unsigned int p2 = bf16bits(b.x) | ((unsigned)bf16bits(b.y) << 16);
        unsigned int p3 = bf16bits(b.z) | ((unsigned)bf16bits(b.w) << 16);
        uint4 o = {p0, p1, p2, p3};
        ((uint4*)xb)[i] = o;
        return;
    }
    bid -= 4096;

    if (bid == 4224) {              // bqs = bq * QSCALE
        #pragma unroll
        for (int j = 0; j < 4; ++j)
            bqs[tid * 4 + j] = bq[tid * 4 + j] * QSCALE;
        return;
    }

    const float* in; bf16_t* out;
    int R, C, c0, r0;
    float scale = 1.0f;
    if (bid < 3072) {               // Wq/Wk/Wv [16][1024][64] -> per-head [64][1024]
        const int p = bid >> 10, r = bid & 1023;
        const int z = r >> 6, rem = r & 63;
        in  = (p == 0 ? Wq : p == 1 ? Wk : Wv) + z * 65536;
        out = WqkvT + p * 1048576 + z * 65536;
        R = 1024; C = 64;
        c0 = (rem & 1) * 32; r0 = (rem >> 1) * 32;
        if (p == 0) scale = QSCALE;
    } else if (bid < 4096) {        // Wo [1024][1024]
        const int r = bid - 3072;
        in = Wo; out = WoT; R = 1024; C = 1024;
        c0 = (r & 31) * 32; r0 = (r >> 5) * 32;
    } else if (bid < 4160) {        // W1 [1024][64]
        const int r = bid - 4096;
        in = W1; out = W1T; R = 1024; C = 64;
        c0 = (r & 1) * 32; r0 = (r >> 1) * 32;
    } else {                        // W2 [64][1024]
        const int r = bid - 4160;
        in = W2; out = W2T; R = 64; C = 1024;
        c0 = (r & 31) * 32; r0 = (r >> 5) * 32;
    }

    {
        int rr = tid >> 3, c4 = (tid & 7) * 4;
        float4 v = *(const float4*)&in[(size_t)(r0 + rr) * C + c0 + c4];
        t[rr][c4 + 0] = v.x * scale;
        t[rr][c4 + 1] = v.y * scale;
        t[rr][c4 + 2] = v.z * scale;
        t[rr][c4 + 3] = v.w * scale;
    }
    __syncthreads();
    {
        int c = tid >> 3, r4 = (tid & 7) * 4;
        ushort4 o;
        o.x = bf16bits(t[r4 + 0][c]);
        o.y = bf16bits(t[r4 + 1][c]);
        o.z = bf16bits(t[r4 + 2][c]);
        o.w = bf16bits(t[r4 + 3][c]);
        *(ushort4*)(out + (size_t)(c0 + c) * R + r0 + r4) = o;
    }
}

// ---------------------------------------------------------------------------
// Row LayerNorm over 1024. InT: float or bf16; OutT: float or bf16.
// ---------------------------------------------------------------------------
template<typename InT, typename OutT>
__global__ __launch_bounds__(256) void ln_kernel(
    const InT* __restrict__ in, const float* __restrict__ g,
    const float* __restrict__ bta, OutT* __restrict__ out)
{
    const int row = blockIdx.x;
    const int tid = threadIdx.x;

    float x0, x1, x2, x3;
    if constexpr (sizeof(InT) == 4) {
        float4 xv = ((const float4*)(in + (size_t)row * E_))[tid];
        x0 = xv.x; x1 = xv.y; x2 = xv.z; x3 = xv.w;
    } else {
        ushort4 xv = *(const ushort4*)((const bf16_t*)in + (size_t)row * E_ + tid * 4);
        x0 = (float)__builtin_bit_cast(bf16_t, xv.x);
        x1 = (float)__builtin_bit_cast(bf16_t, xv.y);
        x2 = (float)__builtin_bit_cast(bf16_t, xv.z);
        x3 = (float)__builtin_bit_cast(bf16_t, xv.w);
    }
    float s  = x0 + x1 + x2 + x3;
    float sq = x0 * x0 + x1 * x1 + x2 * x2 + x3 * x3;
    #pragma unroll
    for (int off = 32; off > 0; off >>= 1) {
        s  += __shfl_down(s, off);
        sq += __shfl_down(sq, off);
    }
    __shared__ float ss[4], ssq[4];
    if ((tid & 63) == 0) { ss[tid >> 6] = s; ssq[tid >> 6] = sq; }
    __syncthreads();
    s  = ss[0] + ss[1] + ss[2] + ss[3];
    sq = ssq[0] + ssq[1] + ssq[2] + ssq[3];

    const float mean = s * (1.0f / E_);
    const float var  = sq * (1.0f / E_) - mean * mean;
    const float rstd = rsqrtf(var + 1e-5f);

    float4 gv = ((const float4*)g)[tid];
    float4 bv = ((const float4*)bta)[tid];
    float o0 = (x0 - mean) * rstd * gv.x + bv.x;
    float o1 = (x1 - mean) * rstd * gv.y + bv.y;
    float o2 = (x2 - mean) * rstd * gv.z + bv.z;
    float o3 = (x3 - mean) * rstd * gv.w + bv.w;
    if constexpr (sizeof(OutT) == 4) {
        float4 o = {o0, o1, o2, o3};
        ((float4*)((float*)out + (size_t)row * E_))[tid] = o;
    } else {
        ushort4 o;
        o.x = bf16bits(o0); o.y = bf16bits(o1);
        o.z = bf16bits(o2); o.w = bf16bits(o3);
        *(ushort4*)((bf16_t*)out + (size_t)row * E_ + tid * 4) = o;
    }
}

// ---------------------------------------------------------------------------
extern "C" void kernel_launch(void* const* d_in, const int* in_sizes, int n_in,
                              void* d_out, int out_size, void* d_ws, size_t ws_size,
                              hipStream_t stream)
{
    const float* x    = (const float*)d_in[0];
    const int*   mask = (const int*)d_in[1];
    const float* Wq   = (const float*)d_in[2];
    const float* bq   = (const float*)d_in[3];
    const float* Wk   = (const float*)d_in[4];
    const float* bk   = (const float*)d_in[5];
    const float* Wv   = (const float*)d_in[6];
    const float* bv   = (const float*)d_in[7];
    const float* Wo   = (const float*)d_in[8];
    const float* bo   = (const float*)d_in[9];
    const float* g1   = (const float*)d_in[10];
    const float* b1   = (const float*)d_in[11];
    const float* W1   = (const float*)d_in[12];
    const float* c1   = (const float*)d_in[13];
    const float* W2   = (const float*)d_in[14];
    const float* c2   = (const float*)d_in[15];
    const float* g2   = (const float*)d_in[16];
    const float* b2   = (const float*)d_in[17];

    char* W = (char*)d_ws;                       // peak ~92.6 MB
    bf16_t* xb    = (bf16_t*)(W + 0);            // 16 MB
    bf16_t* WqkvT = (bf16_t*)(W + 16777216);     //  6 MB [3][1024 n][1024 k]
    bf16_t* WoT   = (bf16_t*)(W + 23068672);     //  2 MB
    bf16_t* W1T   = (bf16_t*)(W + 25165824);     //  128K
    bf16_t* W2T   = (bf16_t*)(W + 25296896);     //  128K
    bf16_t* qbuf  = (bf16_t*)(W + 25427968);     // 16 MB [b,s,h,d]
    bf16_t* kbuf  = (bf16_t*)(W + 42205184);     // 16 MB [b][ci][h,d] compact
    bf16_t* vtc   = (bf16_t*)(W + 58982400);     // 16 MB [bh][d][ci] compact
    bf16_t* ctx   = (bf16_t*)(W + 75759616);     // 16 MB
    bf16_t* t1b   = (bf16_t*)(W + 25427968);     // over qbuf (dead after attn)
    bf16_t* hb    = (bf16_t*)(W + 42205184);     // over kbuf (dead after attn)
    bf16_t* f1b   = (bf16_t*)(W + 0);            // over xb (dead after GEMMs)
    bf16_t* f2b   = (bf16_t*)(W + 58982400);     // over vtc (dead after attn)
    int*    sidx  = (int*)(W + 92536832);        // 32 KB
    int*    nkv   = (int*)(W + 92569600);        // 16 B (pad to 64)
    float*  bqs   = (float*)(W + 92569664);      // 4 KB
    float*  out   = (float*)d_out;

    // fused prep (1/sqrt(S)*log2e folded into Wq and bqs)
    prep_all<<<8321, 256, 0, stream>>>(x, xb, Wq, Wk, Wv, WqkvT,
                                       Wo, WoT, W1, W1T, W2, W2T, bq, bqs);

    // mask scan -> sidx / nkv
    compact_mask<<<4, 256, 0, stream>>>(mask, sidx, nkv);

    // merged Q + compacted-KV projection (1536 blocks)
    gemm_bf16<128, 128, 3><<<dim3(1536), 256, 0, stream>>>(
        xb, WqkvT, qbuf, kbuf, vtc, bqs, bk, bv, sidx, nkv, M_, 1024, 1024);

    // attention over compacted keys
    attn_mfma<<<dim3(1024), 256, 0, stream>>>(qbuf, kbuf, vtc, nkv, ctx);

    // output projection -> bf16 t1
    gemm_bf16<128, 128, 0><<<dim3(8, 64), 256, 0, stream>>>(
        ctx, WoT, t1b, nullptr, nullptr, bo, nullptr, nullptr, nullptr, nullptr,
        M_, 1024, 1024);

    ln_kernel<bf16_t, bf16_t><<<8192, 256, 0, stream>>>(t1b, g1, b1, hb);

    // FFN1 (N=64) + exact GELU -> bf16
    gemm_bf16<32, 64, 1><<<dim3(1, 256), 256, 0, stream>>>(
        hb, W1T, f1b, nullptr, nullptr, c1, nullptr, nullptr, nullptr, nullptr,
        M_, 64, 1024);

    // FFN2 (K=64) -> bf16
    gemm_bf16<128, 128, 0><<<dim3(8, 64), 256, 0, stream>>>(
        f1b, W2T, f2b, nullptr, nullptr, c2, nullptr, nullptr, nullptr, nullptr,
        M_, 1024, 64);

    ln_kernel<bf16_t, float><<<8192, 256, 0, stream>>>(f2b, g2, b2, out);
}